// Round 2
// baseline (747.373 us; speedup 1.0000x reference)
//
#include <hip/hip_runtime.h>
#include <math.h>

typedef unsigned short u16;
typedef unsigned int u32;
typedef __attribute__((ext_vector_type(8))) short short8;
typedef __attribute__((ext_vector_type(4))) float f32x4;

__device__ __forceinline__ u16 f2bf(float f) {
    u32 u = __float_as_uint(f);
    u = u + 0x7fffu + ((u >> 16) & 1u);
    return (u16)(u >> 16);
}
__device__ __forceinline__ float bf2f(u16 h) { return __uint_as_float(((u32)h) << 16); }

__device__ __forceinline__ f32x4 mfma16(short8 a, short8 b, f32x4 c) {
    return __builtin_amdgcn_mfma_f32_16x16x32_bf16(a, b, c, 0, 0, 0);
}

__device__ __forceinline__ uint4 pack8(float4 a, float4 b) {
    uint4 r;
    r.x = (u32)f2bf(a.x) | ((u32)f2bf(a.y) << 16);
    r.y = (u32)f2bf(a.z) | ((u32)f2bf(a.w) << 16);
    r.z = (u32)f2bf(b.x) | ((u32)f2bf(b.y) << 16);
    r.w = (u32)f2bf(b.z) | ((u32)f2bf(b.w) << 16);
    return r;
}

// Async global->LDS 16B: LDS dest is wave-uniform base + lane*16.
#define GLOAD_LDS16(gsrc, ldst)                                                      \
    __builtin_amdgcn_global_load_lds(                                                \
        (__attribute__((address_space(1))) u32*)(gsrc),                              \
        (__attribute__((address_space(3))) u32*)(ldst), 16, 0, 0)

// ===========================================================================
// Fused weight prep (one launch).
// ===========================================================================
__device__ __forceinline__ void prep1_item(const float* __restrict__ w,
                                           u16* __restrict__ o, int i)
{
    int j = i & 7; int kx = j >> 1, cp = j & 1;
    int r = i >> 3;
    int co = r & 31; int r2 = r >> 5;
    int ky = r2 & 3; int h = r2 >> 2;
    int ci = 2 * h + cp;
    o[i] = (ci < 3) ? f2bf(w[((co * 3 + ci) * 16) + ky * 4 + kx]) : (u16)0;
}
__device__ __forceinline__ void prepc_item(const float* __restrict__ w,
                                           u16* __restrict__ o, int CIN, int COUT, int i)
{
    int j = i & 7; int r = i >> 3;
    int co = r % COUT; int r2 = r / COUT;
    int tap = r2 & 15; int ch = r2 >> 4;
    int ci = ch * 8 + j;
    o[i] = f2bf(w[((size_t)co * CIN + ci) * 16 + tap]);
}
__device__ __forceinline__ void prepd_item(const float* __restrict__ w,
                                           u16* __restrict__ o, int CIN, int COUT,
                                           int COPAD, int i)
{
    int j = i & 7; int r = i >> 3;
    int co = r % COPAD; int r2 = r / COPAD;
    int t16 = r2 & 15; int ch = r2 >> 4;
    int py = t16 >> 3, px = (t16 >> 2) & 1, qq = t16 & 3;
    int ta = qq >> 1, tb = qq & 1;
    int ky = py + 2 * ta, kx = px + 2 * tb;
    int ci = ch * 8 + j;
    o[i] = (co < COUT) ? f2bf(w[(((size_t)ci * COUT + co) * 16) + ky * 4 + kx]) : (u16)0;
}

__global__ __launch_bounds__(256) void prep_all(
    const float* __restrict__ ew1, const float* __restrict__ ew2,
    const float* __restrict__ ew3, const float* __restrict__ ew4,
    const float* __restrict__ dw1, const float* __restrict__ dw2,
    const float* __restrict__ dw3, const float* __restrict__ dw4,
    u16* __restrict__ w1c, u16* __restrict__ wc2,
    u16* __restrict__ wc3, u16* __restrict__ wc4,
    u16* __restrict__ wd1, u16* __restrict__ wd2,
    u16* __restrict__ wd3, u16* __restrict__ wd4)
{
    int i = blockIdx.x * 256 + threadIdx.x;
    if (i < 2048) { prep1_item(ew1, w1c, i); return; }
    i -= 2048;
    if (i < 32768)  { prepc_item(ew2, wc2, 32, 64, i); return; }
    i -= 32768;
    if (i < 131072) { prepc_item(ew3, wc3, 64, 128, i); return; }
    i -= 131072;
    if (i < 131072) { prepc_item(ew4, wc4, 128, 64, i); return; }
    i -= 131072;
    if (i < 131072) { prepd_item(dw1, wd1, 64, 128, 128, i); return; }
    i -= 131072;
    if (i < 131072) { prepd_item(dw2, wd2, 128, 64, 64, i); return; }
    i -= 131072;
    if (i < 32768)  { prepd_item(dw3, wd3, 64, 32, 32, i); return; }
    i -= 32768;
    if (i < 8192)   { prepd_item(dw4, wd4, 32, 3, 16, i); return; }
}

// ===========================================================================
// Generic conv (k=4,s=2,p=1) implicit-GEMM MFMA kernel (global_load_lds).
// ===========================================================================
template<int CIN, int COUT, int COTILE, int H2, int W2, int NSEG, int MB,
         int MBW, int NWF, int RELU, int STOREZ>
__global__ __launch_bounds__(256) void conv_mfma(
    const u16* __restrict__ in, const u16* __restrict__ wcvt,
    const float* __restrict__ bias, u16* __restrict__ outp,
    float* __restrict__ z32)
{
    constexpr int CHUNKS = CIN / 8, CGI = CIN / 8, CGO = COUT / 8;
    constexpr int HIN = H2 * 2, WIN = W2 * 2, SLOTW = 35;
    constexpr int NF = COTILE / 16, WM = MB / MBW, WN = NF / NWF;
    static_assert(WM * WN == 4, "wave layout");
    constexpr int TBu = MB * 4 * SLOTW, WBu = 16 * COTILE;
    constexpr int EBu = (MB * 16 * COTILE * 2 + 15) / 16;
    constexpr int SM = (TBu + WBu) > EBu ? (TBu + WBu) : EBu;
    __shared__ uint4 smem[SM];
    uint4* T = smem; uint4* wS = smem + TBu;
    u16* E = (u16*)smem;

    const int tid = threadIdx.x, wid = tid >> 6, lane = tid & 63;
    const int q = lane >> 4, lm = lane & 15;
    const int wm = wid / WN, wn = wid % WN;
    const int cobase = blockIdx.y * COTILE;
    const int mbase = blockIdx.x * MB;

    f32x4 acc[MBW][NWF];
    #pragma unroll
    for (int a = 0; a < MBW; ++a)
        #pragma unroll
        for (int b = 0; b < NWF; ++b) {
            acc[a][b][0] = 0.f; acc[a][b][1] = 0.f;
            acc[a][b][2] = 0.f; acc[a][b][3] = 0.f;
        }

    for (int ch = 0; ch < CHUNKS; ++ch) {
        __syncthreads();
        for (int ib = 0; ib < TBu; ib += 256) {
            int i = ib + tid;
            uint4* ldst = T + ib + (wid << 6);
            if (i < TBu) {
                int mb = i / (4 * SLOTW), r2 = i % (4 * SLOTW);
                int r = r2 / SLOTW, s = r2 % SLOTW;
                int mbg = mbase + mb;
                int n = mbg / (H2 * NSEG), rr = mbg % (H2 * NSEG);
                int oy = rr / NSEG, ox0 = (rr % NSEG) << 4;
                int iy = 2 * oy - 1 + r, ix = 2 * ox0 - 1 + s;
                if ((unsigned)iy < (unsigned)HIN && (unsigned)ix < (unsigned)WIN) {
                    GLOAD_LDS16(in + (size_t)(((n * CGI + ch) * HIN + iy) * WIN + ix) * 8, ldst);
                } else {
                    uint4 zz = {0u, 0u, 0u, 0u};
                    T[i] = zz;
                }
            }
        }
        for (int ib = 0; ib < WBu; ib += 256) {
            int i = ib + tid;
            int tap = i / COTILE, co = i % COTILE;
            GLOAD_LDS16(wcvt + (size_t)((ch * 16 + tap) * COUT + cobase + co) * 8,
                        wS + ib + (wid << 6));
        }
        __syncthreads();
        #pragma unroll
        for (int ky = 0; ky < 4; ++ky) {
            short8 Af[MBW]; short8 Bf[NWF];
            #pragma unroll
            for (int im = 0; im < MBW; ++im) {
                int mb = wm * MBW + im;
                Af[im] = *(const short8*)(T + (mb * 4 + ky) * SLOTW + 2 * lm + q);
            }
            #pragma unroll
            for (int inf = 0; inf < NWF; ++inf)
                Bf[inf] = *(const short8*)(wS + (ky * 4 + q) * COTILE + wn * NWF * 16 + inf * 16 + lm);
            #pragma unroll
            for (int im = 0; im < MBW; ++im)
                #pragma unroll
                for (int inf = 0; inf < NWF; ++inf)
                    acc[im][inf] = mfma16(Af[im], Bf[inf], acc[im][inf]);
        }
    }
    __syncthreads();
    #pragma unroll
    for (int inf = 0; inf < NWF; ++inf) {
        int col = wn * NWF * 16 + inf * 16 + lm;
        float bv = bias[cobase + col];
        #pragma unroll
        for (int im = 0; im < MBW; ++im) {
            int pixb = (wm * MBW + im) * 16 + q * 4;
            #pragma unroll
            for (int r = 0; r < 4; ++r) {
                float v = acc[im][inf][r] + bv;
                if (RELU) v = fmaxf(v, 0.f);
                E[(pixb + r) * COTILE + col] = f2bf(v);
            }
        }
    }
    __syncthreads();
    for (int i = tid; i < MB * 16 * (COTILE / 8); i += 256) {
        int pix = i / (COTILE / 8), cg = i % (COTILE / 8);
        int mb = pix >> 4, m = pix & 15;
        int mbg = mbase + mb;
        int n = mbg / (H2 * NSEG), rr = mbg % (H2 * NSEG);
        int oy = rr / NSEG, ox0 = (rr % NSEG) << 4;
        int ox = ox0 + m;
        if (ox < W2)
            *(uint4*)(outp + (size_t)(((n * CGO + cobase / 8 + cg) * H2 + oy) * W2 + ox) * 8) =
                *(uint4*)(E + pix * COTILE + cg * 8);
    }
    if (STOREZ) {
        for (int i = tid; i < MB * 16 * COTILE; i += 256) {
            int pix = i / COTILE, co = i % COTILE;
            int mb = pix >> 4, m = pix & 15;
            int mbg = mbase + mb;
            int n = mbg / (H2 * NSEG), rr = mbg % (H2 * NSEG);
            int oy = rr / NSEG, ox0 = (rr % NSEG) << 4;
            int ox = ox0 + m;
            if (ox < W2)
                z32[(size_t)((n * COUT + cobase + co) * H2 + oy) * W2 + ox] =
                    bf2f(E[pix * COTILE + co]);
        }
    }
}

// ===========================================================================
// conv1 (CIN=3): staging now vectorized (float4 covers the 4 kx taps);
// scalar fallback only at image edges (2/112 columns).
// ===========================================================================
__global__ __launch_bounds__(256) void conv1_mfma(
    const float* __restrict__ x, const u16* __restrict__ w1c,
    const float* __restrict__ bias, u16* __restrict__ outp)
{
    constexpr int MB = 16, MBW = 4, NWF = 2, COTILE = 32, W2 = 112, H2 = 112, NSEG = 7;
    constexpr int TBu = MB * 2 * 64, WBu = 256;
    __shared__ uint4 smem[TBu + WBu];
    uint4* T1 = smem; uint4* w1S = smem + TBu;
    u16* E = (u16*)smem;

    const int tid = threadIdx.x, wid = tid >> 6, lane = tid & 63;
    const int q = lane >> 4, lm = lane & 15;
    const int wm = wid;
    const int mbase = blockIdx.x * MB;

    f32x4 acc[MBW][NWF];
    #pragma unroll
    for (int a = 0; a < MBW; ++a)
        #pragma unroll
        for (int b = 0; b < NWF; ++b) {
            acc[a][b][0] = 0.f; acc[a][b][1] = 0.f;
            acc[a][b][2] = 0.f; acc[a][b][3] = 0.f;
        }

    for (int i = tid; i < TBu; i += 256) {
        int mb = i >> 7; int r = i & 127;
        int h = r >> 6; int r2 = r & 63;
        int ky = r2 >> 4; int m = r2 & 15;
        int mbg = mbase + mb;
        int n = mbg / (H2 * NSEG), rr = mbg % (H2 * NSEG);
        int oy = rr / NSEG, ox0 = (rr % NSEG) << 4;
        int iy = 2 * oy - 1 + ky;
        int ixb = 2 * (ox0 + m) - 1;
        int ci0 = 2 * h;
        uint4 vv;
        const float* rowp = x + ((size_t)(n * 3 + ci0) * 224 + iy) * 224;
        if ((unsigned)iy < 224u && ixb >= 0 && ixb <= 220) {
            // interior: 4 kx taps = 4 contiguous floats (dword-aligned dwordx4)
            float4 a = *(const float4*)(rowp + ixb);
            float4 bq;
            if (h == 0) bq = *(const float4*)(rowp + 224 * 224 + ixb);
            else { bq.x = 0.f; bq.y = 0.f; bq.z = 0.f; bq.w = 0.f; }
            vv.x = (u32)f2bf(a.x) | ((u32)f2bf(bq.x) << 16);
            vv.y = (u32)f2bf(a.y) | ((u32)f2bf(bq.y) << 16);
            vv.z = (u32)f2bf(a.z) | ((u32)f2bf(bq.z) << 16);
            vv.w = (u32)f2bf(a.w) | ((u32)f2bf(bq.w) << 16);
        } else {
            u32 u[4];
            #pragma unroll
            for (int kx = 0; kx < 4; ++kx) {
                float v0 = 0.f, v1 = 0.f;
                int ix = ixb + kx;
                if ((unsigned)iy < 224u && (unsigned)ix < 224u) {
                    v0 = rowp[ix];
                    if (ci0 + 1 < 3) v1 = rowp[224 * 224 + ix];
                }
                u[kx] = (u32)f2bf(v0) | ((u32)f2bf(v1) << 16);
            }
            vv.x = u[0]; vv.y = u[1]; vv.z = u[2]; vv.w = u[3];
        }
        T1[i] = vv;
    }
    if (tid < 256) {
        w1S[tid] = *(const uint4*)(w1c + (size_t)tid * 8);
    }
    __syncthreads();
    #pragma unroll
    for (int h = 0; h < 2; ++h) {
        short8 Af[MBW]; short8 Bf[NWF];
        #pragma unroll
        for (int im = 0; im < MBW; ++im) {
            int mb = wm * MBW + im;
            Af[im] = *(const short8*)(T1 + (mb * 2 + h) * 64 + lane);
        }
        #pragma unroll
        for (int inf = 0; inf < NWF; ++inf)
            Bf[inf] = *(const short8*)(w1S + (h * 4 + q) * 32 + inf * 16 + lm);
        #pragma unroll
        for (int im = 0; im < MBW; ++im)
            #pragma unroll
            for (int inf = 0; inf < NWF; ++inf)
                acc[im][inf] = mfma16(Af[im], Bf[inf], acc[im][inf]);
    }
    __syncthreads();
    #pragma unroll
    for (int inf = 0; inf < NWF; ++inf) {
        int col = inf * 16 + lm;
        float bv = bias[col];
        #pragma unroll
        for (int im = 0; im < MBW; ++im) {
            int pixb = (wm * MBW + im) * 16 + q * 4;
            #pragma unroll
            for (int r = 0; r < 4; ++r) {
                float v = fmaxf(acc[im][inf][r] + bv, 0.f);
                E[(pixb + r) * COTILE + col] = f2bf(v);
            }
        }
    }
    __syncthreads();
    for (int i = tid; i < MB * 16 * (COTILE / 8); i += 256) {
        int pix = i / (COTILE / 8), cg = i % (COTILE / 8);
        int mb = pix >> 4, m = pix & 15;
        int mbg = mbase + mb;
        int n = mbg / (H2 * NSEG), rr = mbg % (H2 * NSEG);
        int oy = rr / NSEG, ox0 = (rr % NSEG) << 4;
        int ox = ox0 + m;
        *(uint4*)(outp + (size_t)(((n * 4 + cg) * H2 + oy) * W2 + ox) * 8) =
            *(uint4*)(E + pix * COTILE + cg * 8);
    }
}

// ===========================================================================
// Parity-split deconv (kept only for deconv1 whose input is L2-resident).
// ===========================================================================
template<int CIN, int COUT, int COPAD, int COTILE, int Hp, int Wp, int NSEG,
         int MB, int MBW, int NWF, int RELU>
__global__ __launch_bounds__(256) void deconv_mfma(
    const u16* __restrict__ in, const u16* __restrict__ dcvt,
    const float* __restrict__ bias, u16* __restrict__ outp)
{
    constexpr int CHUNKS = CIN / 8, CGI = CIN / 8, CGO = COUT / 8;
    constexpr int SLOTW = 17;
    constexpr int NF = COTILE / 16, WM = MB / MBW, WN = NF / NWF;
    static_assert(WM * WN == 4, "wave layout");
    constexpr int BPP = 64 * Hp * NSEG / MB;
    constexpr int TBu = MB * 2 * SLOTW, WBu = 4 * COTILE;
    constexpr int EBu = (MB * 16 * COTILE * 2 + 15) / 16;
    constexpr int SM = (TBu + WBu) > EBu ? (TBu + WBu) : EBu;
    __shared__ uint4 smem[SM];
    uint4* T = smem; uint4* wS = smem + TBu;
    u16* E = (u16*)smem;

    const int tid = threadIdx.x, wid = tid >> 6, lane = tid & 63;
    const int q = lane >> 4, lm = lane & 15;
    const int wm = wid / WN, wn = wid % WN;
    const int par = blockIdx.x / BPP;
    const int py = par >> 1, px = par & 1;
    const int mbase = (blockIdx.x % BPP) * MB;
    const int cobase = blockIdx.y * COTILE;

    f32x4 acc[MBW][NWF];
    #pragma unroll
    for (int a = 0; a < MBW; ++a)
        #pragma unroll
        for (int b = 0; b < NWF; ++b) {
            acc[a][b][0] = 0.f; acc[a][b][1] = 0.f;
            acc[a][b][2] = 0.f; acc[a][b][3] = 0.f;
        }

    for (int ch = 0; ch < CHUNKS; ++ch) {
        __syncthreads();
        for (int ib = 0; ib < TBu; ib += 256) {
            int i = ib + tid;
            uint4* ldst = T + ib + (wid << 6);
            if (i < TBu) {
                int mb = i / (2 * SLOTW), r2 = i % (2 * SLOTW);
                int rr_ = r2 / SLOTW, s = r2 % SLOTW;
                int mbg = mbase + mb;
                int n = mbg / (Hp * NSEG), rm = mbg % (Hp * NSEG);
                int oyp = rm / NSEG, u0 = (rm % NSEG) << 4;
                int iy = oyp + (1 - py) - 1 + rr_;
                int ix = u0 + (1 - px) - 1 + s;
                if ((unsigned)iy < (unsigned)Hp && (unsigned)ix < (unsigned)Wp) {
                    GLOAD_LDS16(in + (size_t)(((n * CGI + ch) * Hp + iy) * Wp + ix) * 8, ldst);
                } else {
                    uint4 zz = {0u, 0u, 0u, 0u};
                    T[i] = zz;
                }
            }
        }
        for (int ib = 0; ib < WBu; ib += 256) {
            int i = ib + tid;
            if (i < WBu) {
                int qq = i / COTILE, co = i % COTILE;
                GLOAD_LDS16(dcvt + (size_t)((ch * 16 + par * 4 + qq) * COPAD + cobase + co) * 8,
                            wS + ib + (wid << 6));
            }
        }
        __syncthreads();
        {
            short8 Af[MBW]; short8 Bf[NWF];
            #pragma unroll
            for (int im = 0; im < MBW; ++im) {
                int mb = wm * MBW + im;
                Af[im] = *(const short8*)(T + (mb * 2 + (1 - (q >> 1))) * SLOTW + lm + 1 - (q & 1));
            }
            #pragma unroll
            for (int inf = 0; inf < NWF; ++inf)
                Bf[inf] = *(const short8*)(wS + q * COTILE + wn * NWF * 16 + inf * 16 + lm);
            #pragma unroll
            for (int im = 0; im < MBW; ++im)
                #pragma unroll
                for (int inf = 0; inf < NWF; ++inf)
                    acc[im][inf] = mfma16(Af[im], Bf[inf], acc[im][inf]);
        }
    }
    __syncthreads();
    #pragma unroll
    for (int inf = 0; inf < NWF; ++inf) {
        int col = wn * NWF * 16 + inf * 16 + lm;
        float bv = bias[cobase + col];
        #pragma unroll
        for (int im = 0; im < MBW; ++im) {
            int pixb = (wm * MBW + im) * 16 + q * 4;
            #pragma unroll
            for (int r = 0; r < 4; ++r) {
                float v = acc[im][inf][r] + bv;
                if (RELU) v = fmaxf(v, 0.f);
                E[(pixb + r) * COTILE + col] = f2bf(v);
            }
        }
    }
    __syncthreads();
    for (int i = tid; i < MB * 16 * (COTILE / 8); i += 256) {
        int pix = i / (COTILE / 8), cg = i % (COTILE / 8);
        int mb = pix >> 4, m = pix & 15;
        int mbg = mbase + mb;
        int n = mbg / (Hp * NSEG), rm = mbg % (Hp * NSEG);
        int oyp = rm / NSEG, u0 = (rm % NSEG) << 4;
        int u = u0 + m;
        if (u < Wp) {
            int ox = 2 * u + (px ? 0 : 1);
            int oy = 2 * oyp + (py ? 0 : 1);
            *(uint4*)(outp + (size_t)(((n * CGO + cobase / 8 + cg) * (2 * Hp) + oy) * (2 * Wp) + ox) * 8) =
                *(uint4*)(E + pix * COTILE + cg * 8);
        }
    }
}

// ===========================================================================
// All-parity deconv: one block computes all 4 parity quadrants of its tile
// (deconv4 pattern generalized). Kills the 4x input re-read and the stride-2
// pixel stores of the parity-split version. 2-pass row-parity epilogue via a
// cg-XOR-swizzled E buffer (conflict-free LDS reads + 512B-contiguous stores).
// ===========================================================================
template<int CIN, int COUT, int COPAD, int COTILE, int Hp, int Wp, int NSEG,
         int MB, int MBW, int NWF, int RELU>
__global__ __launch_bounds__(256) void deconv_all(
    const u16* __restrict__ in, const u16* __restrict__ dcvt,
    const float* __restrict__ bias, u16* __restrict__ outp)
{
    constexpr int CHUNKS = CIN / 8, CGI = CIN / 8, CGO = COUT / 8;
    constexpr int TROW = 3, TCOL = 18;
    constexpr int NF = COTILE / 16, WM = MB / MBW, WN = NF / NWF;
    static_assert(WM * WN == 4, "wave layout");
    constexpr int TBu = MB * TROW * TCOL;
    constexpr int WBu = 16 * COTILE;
    constexpr int EBu = MB * 16 * 2 * COTILE / 8;   // 2-parity bf16 E, uint4 units
    constexpr int SM = (TBu + WBu) > EBu ? (TBu + WBu) : EBu;
    __shared__ uint4 smem[SM];
    uint4* T = smem; uint4* wS = smem + TBu;
    u16* E = (u16*)smem;

    const int tid = threadIdx.x, wid = tid >> 6, lane = tid & 63;
    const int q = lane >> 4, lm = lane & 15;
    const int wm = wid / WN, wn = wid % WN;
    const int mbase = blockIdx.x * MB;
    const int cobase = blockIdx.y * COTILE;

    f32x4 acc[4][MBW][NWF];
    #pragma unroll
    for (int p = 0; p < 4; ++p)
        #pragma unroll
        for (int a = 0; a < MBW; ++a)
            #pragma unroll
            for (int b = 0; b < NWF; ++b) {
                acc[p][a][b][0] = 0.f; acc[p][a][b][1] = 0.f;
                acc[p][a][b][2] = 0.f; acc[p][a][b][3] = 0.f;
            }

    for (int ch = 0; ch < CHUNKS; ++ch) {
        __syncthreads();
        for (int ib = 0; ib < TBu; ib += 256) {
            int i = ib + tid;
            uint4* ldst = T + ib + (wid << 6);
            if (i < TBu) {
                int mb = i / (TROW * TCOL), r2 = i % (TROW * TCOL);
                int r = r2 / TCOL, s = r2 % TCOL;
                int mbg = mbase + mb;
                int n = mbg / (Hp * NSEG), rm = mbg % (Hp * NSEG);
                int oyp = rm / NSEG, u0 = (rm % NSEG) << 4;
                int iy = oyp - 1 + r;
                int ix = u0 - 1 + s;
                if ((unsigned)iy < (unsigned)Hp && (unsigned)ix < (unsigned)Wp) {
                    GLOAD_LDS16(in + (size_t)(((n * CGI + ch) * Hp + iy) * Wp + ix) * 8, ldst);
                } else {
                    uint4 zz = {0u, 0u, 0u, 0u};
                    T[i] = zz;
                }
            }
        }
        for (int ib = 0; ib < WBu; ib += 256) {
            int i = ib + tid;
            if (i < WBu) {
                int t16 = i / COTILE, co = i % COTILE;
                GLOAD_LDS16(dcvt + (size_t)((ch * 16 + t16) * COPAD + cobase + co) * 8,
                            wS + ib + (wid << 6));
            }
        }
        __syncthreads();
        #pragma unroll
        for (int par = 0; par < 4; ++par) {
            const int py = par >> 1, px = par & 1;
            short8 Bf[NWF];
            #pragma unroll
            for (int inf = 0; inf < NWF; ++inf)
                Bf[inf] = *(const short8*)(wS + (par * 4 + q) * COTILE + wn * NWF * 16 + inf * 16 + lm);
            #pragma unroll
            for (int im = 0; im < MBW; ++im) {
                int mb = wm * MBW + im;
                short8 Af = *(const short8*)(T + (mb * TROW + (2 - py - (q >> 1))) * TCOL
                                             + lm + 2 - px - (q & 1));
                #pragma unroll
                for (int inf = 0; inf < NWF; ++inf)
                    acc[par][im][inf] = mfma16(Af, Bf[inf], acc[par][im][inf]);
            }
        }
    }
    // ---- epilogue: pass pp handles output rows oy = 2*oyp + (1-pp) ----
    #pragma unroll
    for (int pp = 0; pp < 2; ++pp) {
        __syncthreads();
        #pragma unroll
        for (int inf = 0; inf < NWF; ++inf) {
            int col = wn * NWF * 16 + inf * 16 + lm;
            float bv = bias[cobase + col];
            #pragma unroll
            for (int im = 0; im < MBW; ++im) {
                #pragma unroll
                for (int r = 0; r < 4; ++r) {
                    int m = q * 4 + r;
                    int pix = (wm * MBW + im) * 16 + m;
                    int colx = col ^ ((m & (COTILE / 8 - 1)) << 3);
                    #pragma unroll
                    for (int pxx = 0; pxx < 2; ++pxx) {
                        float v = acc[pp * 2 + pxx][im][inf][r] + bv;
                        if (RELU) v = fmaxf(v, 0.f);
                        E[(pix * 2 + pxx) * COTILE + colx] = f2bf(v);
                    }
                }
            }
        }
        __syncthreads();
        const int dy = 1 - pp;
        for (int i = tid; i < (COTILE / 8) * MB * 32; i += 256) {
            int xx = i & 31;
            int t = i >> 5;
            int mb = t & (MB - 1), cg = t / MB;
            int m = xx >> 1;
            int pxx = 1 - (xx & 1);
            int pix = mb * 16 + m;
            int mbg = mbase + mb;
            int n = mbg / (Hp * NSEG), rm = mbg % (Hp * NSEG);
            int oyp = rm / NSEG, u0 = (rm % NSEG) << 4;
            int u = u0 + m;
            if (u < Wp) {
                int oy = 2 * oyp + dy;
                int ox = 2 * u + (xx & 1);
                int cgx = cg ^ (m & (COTILE / 8 - 1));
                *(uint4*)(outp + (size_t)(((n * CGO + cobase / 8 + cg) * (2 * Hp) + oy) * (2 * Wp) + ox) * 8) =
                    *(uint4*)(E + ((pix * 2 + pxx) * COTILE + cgx * 8));
            }
        }
    }
}

// ===========================================================================
// deconv4: all 4 parity quadrants per block; fused sigmoid + recon-loss.
// ===========================================================================
__global__ __launch_bounds__(256) void deconv4_mfma(
    const u16* __restrict__ in, const u16* __restrict__ dcvt,
    const float* __restrict__ bias, float* __restrict__ outp,
    const float* __restrict__ xref, float* __restrict__ bpart)
{
    constexpr int Hp = 112, Wp = 112, NSEG = 7, MB = 16, MBW = 4;
    constexpr int CGI = 4, CHUNKS = 4;
    constexpr int TROW = 3, TCOL = 18;
    constexpr int TBu = MB * TROW * TCOL;   // 864 uint4
    __shared__ uint4 smem[TBu + 1024];
    __shared__ float red[4];
    uint4* T = smem; uint4* wS = smem + TBu;
    float* Ef = (float*)smem;               // 3072 f32 = 12KB

    const int tid = threadIdx.x, wid = tid >> 6, lane = tid & 63;
    const int q = lane >> 4, lm = lane & 15;
    const int wm = wid;
    const int mbase = blockIdx.x * MB;

    f32x4 acc[4][MBW];
    #pragma unroll
    for (int p = 0; p < 4; ++p)
        #pragma unroll
        for (int a = 0; a < MBW; ++a) {
            acc[p][a][0] = 0.f; acc[p][a][1] = 0.f; acc[p][a][2] = 0.f; acc[p][a][3] = 0.f;
        }

    for (int ib = 0; ib < 1024; ib += 256)
        GLOAD_LDS16(dcvt + (size_t)(ib + tid) * 8, wS + ib + (wid << 6));

    for (int ch = 0; ch < CHUNKS; ++ch) {
        __syncthreads();
        for (int ib = 0; ib < TBu; ib += 256) {
            int i = ib + tid;
            uint4* ldst = T + ib + (wid << 6);
            if (i < TBu) {
                int mb = i / (TROW * TCOL), r2 = i % (TROW * TCOL);
                int r = r2 / TCOL, s = r2 % TCOL;
                int mbg = mbase + mb;
                int n = mbg / (Hp * NSEG), rm = mbg % (Hp * NSEG);
                int oyp = rm / NSEG, u0 = (rm % NSEG) << 4;
                int iy = oyp - 1 + r;
                int ix = u0 - 1 + s;
                if ((unsigned)iy < (unsigned)Hp && (unsigned)ix < (unsigned)Wp) {
                    GLOAD_LDS16(in + (size_t)(((n * CGI + ch) * Hp + iy) * Wp + ix) * 8, ldst);
                } else {
                    uint4 zz = {0u, 0u, 0u, 0u};
                    T[i] = zz;
                }
            }
        }
        __syncthreads();
        #pragma unroll
        for (int par = 0; par < 4; ++par) {
            const int py = par >> 1, px = par & 1;
            short8 Bf = *(const short8*)(wS + (ch * 16 + par * 4 + q) * 16 + lm);
            #pragma unroll
            for (int im = 0; im < MBW; ++im) {
                int mb = wm * MBW + im;
                short8 Af = *(const short8*)(T + (mb * TROW + (2 - py - (q >> 1))) * TCOL
                                             + lm + 2 - px - (q & 1));
                acc[par][im] = mfma16(Af, Bf, acc[par][im]);
            }
        }
    }

    __syncthreads();
    if (lm < 3) {
        float bv = bias[lm];
        #pragma unroll
        for (int par = 0; par < 4; ++par)
            #pragma unroll
            for (int im = 0; im < MBW; ++im)
                #pragma unroll
                for (int r = 0; r < 4; ++r)
                    Ef[(((wm * MBW + im) * 16 + q * 4 + r) * 4 + par) * 3 + lm] =
                        acc[par][im][r] + bv;
    }
    __syncthreads();
    float lsum = 0.f;
    #pragma unroll
    for (int k = 0; k < 3; ++k) {
        int i = k * 256 + tid;
        int mb = i / 48, rem = i % 48;
        int row = rem / 24, rem2 = rem % 24;
        int co = rem2 / 8, ox4 = rem2 % 8;
        int mbg = mbase + mb;
        int n = mbg / (Hp * NSEG), rm = mbg % (Hp * NSEG);
        int oyp = rm / NSEG, u0 = (rm % NSEG) << 4;
        int pA = row ? 1 : 3, pB = row ? 0 : 2;
        int uL = 2 * ox4, uH = uL + 1;
        float v0 = Ef[((mb * 16 + uL) * 4 + pA) * 3 + co];
        float v1 = Ef[((mb * 16 + uL) * 4 + pB) * 3 + co];
        float v2 = Ef[((mb * 16 + uH) * 4 + pA) * 3 + co];
        float v3 = Ef[((mb * 16 + uH) * 4 + pB) * 3 + co];
        float4 sv;
        sv.x = 1.f / (1.f + expf(-v0));
        sv.y = 1.f / (1.f + expf(-v1));
        sv.z = 1.f / (1.f + expf(-v2));
        sv.w = 1.f / (1.f + expf(-v3));
        size_t ro = ((size_t)(n * 3 + co) * 224 + 2 * oyp + row) * 224 + 2 * u0 + 4 * ox4;
        float4 x4 = *(const float4*)(xref + ro);
        *(float4*)(outp + ro) = sv;
        float d0 = sv.x - x4.x, d1 = sv.y - x4.y, d2 = sv.z - x4.z, d3 = sv.w - x4.w;
        lsum += d0 * d0 + d1 * d1 + d2 * d2 + d3 * d3;
    }
    #pragma unroll
    for (int off = 32; off > 0; off >>= 1)
        lsum += __shfl_down(lsum, off, 64);
    if (lane == 0) red[wid] = lsum;
    __syncthreads();
    if (tid == 0)
        bpart[blockIdx.x] = red[0] + red[1] + red[2] + red[3];
}

// ===========================================================================
// VQ dot GEMM: M=64, N=4000, K=12544 (14 k-splits). Coalesced cooperative
// staging (was per-thread-own-row = 64 cache lines/instruction) with
// XOR-swizzled LDS layout (write Bs[k8][r^k8], read with same involution).
// ===========================================================================
__global__ __launch_bounds__(256) void vq_gemm(
    const float* __restrict__ z32, const float* __restrict__ emb,
    float* __restrict__ P, float* __restrict__ normp)
{
    __shared__ uint4 As[8 * 64];     // 8KB
    __shared__ uint4 Bs[8 * 256];    // 32KB
    __shared__ float Ns[256 * 8];    // 8KB norm partials [row][k8]
    const int tid = threadIdx.x, wid = tid >> 6, lane = tid & 63;
    const int q = lane >> 4, lm = lane & 15;
    const int jt = blockIdx.x, ks = blockIdx.y;
    const int k8s = tid & 7;         // k8 slice staged by this thread
    const int rb2 = tid >> 3;        // 0..31 row base (B staging)

    f32x4 acc[4][4];
    #pragma unroll
    for (int a = 0; a < 4; ++a)
        #pragma unroll
        for (int b = 0; b < 4; ++b) {
            acc[a][b][0] = 0.f; acc[a][b][1] = 0.f; acc[a][b][2] = 0.f; acc[a][b][3] = 0.f;
        }
    float nsum[8];
    #pragma unroll
    for (int it = 0; it < 8; ++it) nsum[it] = 0.f;

    for (int ch = 0; ch < 14; ++ch) {
        __syncthreads();
        // A: 64 rows x 64 k; 8 lanes x 32B contiguous per row
        #pragma unroll
        for (int it = 0; it < 2; ++it) {
            int i = tid + it * 256;
            int k8 = i & 7, m = i >> 3;
            const float* ap = z32 + (size_t)m * 12544 + ks * 896 + ch * 64 + k8 * 8;
            float4 f0 = *(const float4*)(ap);
            float4 f1 = *(const float4*)(ap + 4);
            As[k8 * 64 + (m ^ k8)] = pack8(f0, f1);
        }
        // B: 256 rows x 64 k; coalesced; per-row norm partial per k8 slice
        #pragma unroll
        for (int it = 0; it < 8; ++it) {
            int r = rb2 + 32 * it;
            int jg = jt * 256 + r;
            int jc = jg < 4000 ? jg : 3999;
            const float* bp = emb + (size_t)jc * 12544 + ks * 896 + ch * 64 + k8s * 8;
            float4 fa = *(const float4*)(bp);
            float4 fb = *(const float4*)(bp + 4);
            nsum[it] += fa.x * fa.x + fa.y * fa.y + fa.z * fa.z + fa.w * fa.w
                      + fb.x * fb.x + fb.y * fb.y + fb.z * fb.z + fb.w * fb.w;
            Bs[k8s * 256 + (r ^ k8s)] = pack8(fa, fb);
        }
        __syncthreads();
        #pragma unroll
        for (int kk = 0; kk < 2; ++kk) {
            short8 Af[4]; short8 Bf[4];
            int k8x = kk * 4 + q;
            #pragma unroll
            for (int mf = 0; mf < 4; ++mf)
                Af[mf] = *(const short8*)(As + k8x * 64 + ((mf * 16 + lm) ^ k8x));
            #pragma unroll
            for (int nf = 0; nf < 4; ++nf)
                Bf[nf] = *(const short8*)(Bs + k8x * 256 + ((wid * 64 + nf * 16 + lm) ^ k8x));
            #pragma unroll
            for (int mf = 0; mf < 4; ++mf)
                #pragma unroll
                for (int nf = 0; nf < 4; ++nf)
                    acc[mf][nf] = mfma16(Af[mf], Bf[nf], acc[mf][nf]);
        }
    }
    // norm reduce: 8 partials per row
    __syncthreads();
    #pragma unroll
    for (int it = 0; it < 8; ++it)
        Ns[(rb2 + 32 * it) * 8 + k8s] = nsum[it];
    __syncthreads();
    {
        float s = 0.f;
        #pragma unroll
        for (int f = 0; f < 8; ++f) s += Ns[tid * 8 + f];
        int jg2 = jt * 256 + tid;
        if (jg2 < 4000) normp[ks * 4000 + jg2] = s;
    }
    #pragma unroll
    for (int mf = 0; mf < 4; ++mf)
        #pragma unroll
        for (int nf = 0; nf < 4; ++nf) {
            int j = jt * 256 + wid * 64 + nf * 16 + lm;
            if (j < 4000) {
                #pragma unroll
                for (int r = 0; r < 4; ++r) {
                    int b = mf * 16 + q * 4 + r;
                    P[(size_t)(ks * 64 + b) * 4000 + j] = acc[mf][nf][r];
                }
            }
        }
}

// Fused argmin + gather -> Qb + vq partial loss.
__global__ __launch_bounds__(256) void vq_argmin_gather(
    const float* __restrict__ P, const float* __restrict__ normp,
    const float* __restrict__ emb, const float* __restrict__ z32,
    u16* __restrict__ Qb, float* __restrict__ vacc)
{
    const int b = blockIdx.x;
    const int tid = threadIdx.x;
    float best = 3.4e38f;
    int bidx = 0x7fffffff;
    for (int j = tid; j < 4000; j += 256) {
        float dot = 0.f, nrm = 0.f;
        #pragma unroll
        for (int s = 0; s < 14; ++s) {
            dot += P[(size_t)(s * 64 + b) * 4000 + j];
            nrm += normp[s * 4000 + j];
        }
        float d = nrm - 2.f * dot;
        if (d < best) { best = d; bidx = j; }
    }
    __shared__ float sv[256];
    __shared__ int si[256];
    sv[tid] = best; si[tid] = bidx;
    __syncthreads();
    for (int off = 128; off > 0; off >>= 1) {
        if (tid < off) {
            float v2 = sv[tid + off]; int i2 = si[tid + off];
            if (v2 < sv[tid] || (v2 == sv[tid] && i2 < si[tid])) { sv[tid] = v2; si[tid] = i2; }
        }
        __syncthreads();
    }
    const int code = si[0];
    const float* e = emb + (size_t)code * 12544;
    const float* zb = z32 + (size_t)b * 12544;
    float ls = 0.f;
    for (int d = tid; d < 12544; d += 256) {
        float ev = e[d];
        int co = d / 196, rem = d % 196;
        int y = rem / 14, xx = rem % 14;
        Qb[((size_t)((b * 8 + (co >> 3)) * 14 + y) * 14 + xx) * 8 + (co & 7)] = f2bf(ev);
        float df = ev - zb[d];
        ls += df * df;
    }
    #pragma unroll
    for (int off = 32; off > 0; off >>= 1)
        ls += __shfl_down(ls, off, 64);
    if ((tid & 63) == 0) atomicAdd(vacc, ls);
}

__global__ __launch_bounds__(256) void reduce_final(
    const float* __restrict__ bpart, const float* __restrict__ vacc,
    float* __restrict__ tail)
{
    const int tid = threadIdx.x;
    float s = 0.f;
    for (int i = tid; i < 3136; i += 256) s += bpart[i];
    #pragma unroll
    for (int off = 32; off > 0; off >>= 1)
        s += __shfl_down(s, off, 64);
    __shared__ float red[4];
    if ((tid & 63) == 0) red[tid >> 6] = s;
    __syncthreads();
    if (tid == 0) {
        float rsum = red[0] + red[1] + red[2] + red[3];
        float recon = rsum * (1.f / 9633792.f);
        float vq = 1.25f * vacc[0] * (1.f / 802816.f);
        tail[0] = recon + vq;
        tail[1] = recon;
        tail[2] = vq;
    }
}

// ---------------------------------------------------------------------------
extern "C" void kernel_launch(void* const* d_in, const int* in_sizes, int n_in,
                              void* d_out, int out_size, void* d_ws, size_t ws_size,
                              hipStream_t stream)
{
    const float* x   = (const float*)d_in[0];
    const float* ew1 = (const float*)d_in[1];
    const float* eb1 = (const float*)d_in[2];
    const float* ew2 = (const float*)d_in[3];
    const float* eb2 = (const float*)d_in[4];
    const float* ew3 = (const float*)d_in[5];
    const float* eb3 = (const float*)d_in[6];
    const float* ew4 = (const float*)d_in[7];
    const float* eb4 = (const float*)d_in[8];
    const float* emb = (const float*)d_in[9];
    const float* dw1 = (const float*)d_in[10];
    const float* db1 = (const float*)d_in[11];
    const float* dw2 = (const float*)d_in[12];
    const float* db2 = (const float*)d_in[13];
    const float* dw3 = (const float*)d_in[14];
    const float* db3 = (const float*)d_in[15];
    const float* dw4 = (const float*)d_in[16];
    const float* db4 = (const float*)d_in[17];
    float* out = (float*)d_out;

    size_t off = 0;
    char* base = (char*)d_ws;
    auto nxt = [&](size_t bytes) -> char* {
        char* p = base + off;
        off = (off + bytes + 255) & ~(size_t)255;
        return p;
    };
    u16*   A1    = (u16*)nxt(25690112ull * 2);
    u16*   A2    = (u16*)nxt(12845056ull * 2);
    u16*   A3    = (u16*)nxt(6422528ull * 2);
    float* z32   = (float*)nxt(802816ull * 4);
    u16*   Qb    = (u16*)nxt(802816ull * 2);
    float* P     = (float*)nxt(14ull * 64 * 4000 * 4);
    float* normp = (float*)nxt(14ull * 4000 * 4);
    u16*   w1c   = (u16*)nxt(2048ull * 2);
    u16*   wc2   = (u16*)nxt(32768ull * 2);
    u16*   wc3   = (u16*)nxt(131072ull * 2);
    u16*   wc4   = (u16*)nxt(131072ull * 2);
    u16*   wd1   = (u16*)nxt(131072ull * 2);
    u16*   wd2   = (u16*)nxt(131072ull * 2);
    u16*   wd3   = (u16*)nxt(32768ull * 2);
    u16*   wd4   = (u16*)nxt(8192ull * 2);
    float* accp  = (float*)nxt(512);
    float* bpart = (float*)nxt(3136ull * 4);
    u16*   D1 = A3;
    u16*   D2 = A2;
    u16*   D3 = A1;

    hipMemsetAsync(accp, 0, 8, stream);

    prep_all<<<2344, 256, 0, stream>>>(ew1, ew2, ew3, ew4, dw1, dw2, dw3, dw4,
                                       w1c, wc2, wc3, wc4, wd1, wd2, wd3, wd4);

    // ---- encoder ----
    conv1_mfma<<<3136, 256, 0, stream>>>(x, w1c, eb1, A1);
    conv_mfma<32, 64, 64, 56, 56, 4, 16, 8, 2, 1, 0>
        <<<dim3(896, 1), 256, 0, stream>>>(A1, wc2, eb2, A2, nullptr);
    conv_mfma<64, 128, 64, 28, 28, 2, 8, 4, 2, 1, 0>
        <<<dim3(448, 2), 256, 0, stream>>>(A2, wc3, eb3, A3, nullptr);
    conv_mfma<128, 64, 64, 14, 14, 1, 8, 2, 4, 0, 1>
        <<<dim3(112, 1), 256, 0, stream>>>(A3, wc4, eb4, Qb, z32);

    // ---- VQ ----
    vq_gemm<<<dim3(16, 14), 256, 0, stream>>>(z32, emb, P, normp);
    vq_argmin_gather<<<64, 256, 0, stream>>>(P, normp, emb, z32, Qb, accp);

    // ---- decoder ----
    deconv_mfma<64, 128, 128, 64, 14, 14, 1, 8, 4, 2, 1>
        <<<dim3(448, 2), 256, 0, stream>>>(Qb, wd1, db1, D1);
    deconv_all<128, 64, 64, 64, 28, 28, 2, 8, 4, 2, 1>
        <<<dim3(448, 1), 256, 0, stream>>>(D1, wd2, db2, D2);
    deconv_all<64, 32, 32, 32, 56, 56, 4, 16, 4, 2, 1>
        <<<dim3(896, 1), 256, 0, stream>>>(D2, wd3, db3, D3);
    deconv4_mfma<<<3136, 256, 0, stream>>>(D3, wd4, db4, out, x, bpart);

    reduce_final<<<1, 256, 0, stream>>>(bpart, accp, out + 9633792);
}

// Round 3
// 716.681 us; speedup vs baseline: 1.0428x; 1.0428x over previous
//
#include <hip/hip_runtime.h>
#include <math.h>

typedef unsigned short u16;
typedef unsigned int u32;
typedef __attribute__((ext_vector_type(8))) short short8;
typedef __attribute__((ext_vector_type(4))) float f32x4;

__device__ __forceinline__ u16 f2bf(float f) {
    u32 u = __float_as_uint(f);
    u = u + 0x7fffu + ((u >> 16) & 1u);
    return (u16)(u >> 16);
}
__device__ __forceinline__ float bf2f(u16 h) { return __uint_as_float(((u32)h) << 16); }

__device__ __forceinline__ f32x4 mfma16(short8 a, short8 b, f32x4 c) {
    return __builtin_amdgcn_mfma_f32_16x16x32_bf16(a, b, c, 0, 0, 0);
}

__device__ __forceinline__ uint4 pack8(float4 a, float4 b) {
    uint4 r;
    r.x = (u32)f2bf(a.x) | ((u32)f2bf(a.y) << 16);
    r.y = (u32)f2bf(a.z) | ((u32)f2bf(a.w) << 16);
    r.z = (u32)f2bf(b.x) | ((u32)f2bf(b.y) << 16);
    r.w = (u32)f2bf(b.z) | ((u32)f2bf(b.w) << 16);
    return r;
}

// Async global->LDS 16B: LDS dest is wave-uniform base + lane*16.
#define GLOAD_LDS16(gsrc, ldst)                                                      \
    __builtin_amdgcn_global_load_lds(                                                \
        (__attribute__((address_space(1))) u32*)(gsrc),                              \
        (__attribute__((address_space(3))) u32*)(ldst), 16, 0, 0)

// ===========================================================================
// Fused weight prep (one launch).
// ===========================================================================
__device__ __forceinline__ void prep1_item(const float* __restrict__ w,
                                           u16* __restrict__ o, int i)
{
    int j = i & 7; int kx = j >> 1, cp = j & 1;
    int r = i >> 3;
    int co = r & 31; int r2 = r >> 5;
    int ky = r2 & 3; int h = r2 >> 2;
    int ci = 2 * h + cp;
    o[i] = (ci < 3) ? f2bf(w[((co * 3 + ci) * 16) + ky * 4 + kx]) : (u16)0;
}
__device__ __forceinline__ void prepc_item(const float* __restrict__ w,
                                           u16* __restrict__ o, int CIN, int COUT, int i)
{
    int j = i & 7; int r = i >> 3;
    int co = r % COUT; int r2 = r / COUT;
    int tap = r2 & 15; int ch = r2 >> 4;
    int ci = ch * 8 + j;
    o[i] = f2bf(w[((size_t)co * CIN + ci) * 16 + tap]);
}
__device__ __forceinline__ void prepd_item(const float* __restrict__ w,
                                           u16* __restrict__ o, int CIN, int COUT,
                                           int COPAD, int i)
{
    int j = i & 7; int r = i >> 3;
    int co = r % COPAD; int r2 = r / COPAD;
    int t16 = r2 & 15; int ch = r2 >> 4;
    int py = t16 >> 3, px = (t16 >> 2) & 1, qq = t16 & 3;
    int ta = qq >> 1, tb = qq & 1;
    int ky = py + 2 * ta, kx = px + 2 * tb;
    int ci = ch * 8 + j;
    o[i] = (co < COUT) ? f2bf(w[(((size_t)ci * COUT + co) * 16) + ky * 4 + kx]) : (u16)0;
}

__global__ __launch_bounds__(256) void prep_all(
    const float* __restrict__ ew1, const float* __restrict__ ew2,
    const float* __restrict__ ew3, const float* __restrict__ ew4,
    const float* __restrict__ dw1, const float* __restrict__ dw2,
    const float* __restrict__ dw3, const float* __restrict__ dw4,
    u16* __restrict__ w1c, u16* __restrict__ wc2,
    u16* __restrict__ wc3, u16* __restrict__ wc4,
    u16* __restrict__ wd1, u16* __restrict__ wd2,
    u16* __restrict__ wd3, u16* __restrict__ wd4)
{
    int i = blockIdx.x * 256 + threadIdx.x;
    if (i < 2048) { prep1_item(ew1, w1c, i); return; }
    i -= 2048;
    if (i < 32768)  { prepc_item(ew2, wc2, 32, 64, i); return; }
    i -= 32768;
    if (i < 131072) { prepc_item(ew3, wc3, 64, 128, i); return; }
    i -= 131072;
    if (i < 131072) { prepc_item(ew4, wc4, 128, 64, i); return; }
    i -= 131072;
    if (i < 131072) { prepd_item(dw1, wd1, 64, 128, 128, i); return; }
    i -= 131072;
    if (i < 131072) { prepd_item(dw2, wd2, 128, 64, 64, i); return; }
    i -= 131072;
    if (i < 32768)  { prepd_item(dw3, wd3, 64, 32, 32, i); return; }
    i -= 32768;
    if (i < 8192)   { prepd_item(dw4, wd4, 32, 3, 16, i); return; }
}

// ===========================================================================
// Generic conv (k=4,s=2,p=1) implicit-GEMM MFMA kernel (global_load_lds).
// ===========================================================================
template<int CIN, int COUT, int COTILE, int H2, int W2, int NSEG, int MB,
         int MBW, int NWF, int RELU, int STOREZ>
__global__ __launch_bounds__(256) void conv_mfma(
    const u16* __restrict__ in, const u16* __restrict__ wcvt,
    const float* __restrict__ bias, u16* __restrict__ outp,
    float* __restrict__ z32)
{
    constexpr int CHUNKS = CIN / 8, CGI = CIN / 8, CGO = COUT / 8;
    constexpr int HIN = H2 * 2, WIN = W2 * 2, SLOTW = 35;
    constexpr int NF = COTILE / 16, WM = MB / MBW, WN = NF / NWF;
    static_assert(WM * WN == 4, "wave layout");
    constexpr int TBu = MB * 4 * SLOTW, WBu = 16 * COTILE;
    constexpr int EBu = (MB * 16 * COTILE * 2 + 15) / 16;
    constexpr int SM = (TBu + WBu) > EBu ? (TBu + WBu) : EBu;
    __shared__ uint4 smem[SM];
    uint4* T = smem; uint4* wS = smem + TBu;
    u16* E = (u16*)smem;

    const int tid = threadIdx.x, wid = tid >> 6, lane = tid & 63;
    const int q = lane >> 4, lm = lane & 15;
    const int wm = wid / WN, wn = wid % WN;
    const int cobase = blockIdx.y * COTILE;
    const int mbase = blockIdx.x * MB;

    f32x4 acc[MBW][NWF];
    #pragma unroll
    for (int a = 0; a < MBW; ++a)
        #pragma unroll
        for (int b = 0; b < NWF; ++b) {
            acc[a][b][0] = 0.f; acc[a][b][1] = 0.f;
            acc[a][b][2] = 0.f; acc[a][b][3] = 0.f;
        }

    for (int ch = 0; ch < CHUNKS; ++ch) {
        __syncthreads();
        for (int ib = 0; ib < TBu; ib += 256) {
            int i = ib + tid;
            uint4* ldst = T + ib + (wid << 6);
            if (i < TBu) {
                int mb = i / (4 * SLOTW), r2 = i % (4 * SLOTW);
                int r = r2 / SLOTW, s = r2 % SLOTW;
                int mbg = mbase + mb;
                int n = mbg / (H2 * NSEG), rr = mbg % (H2 * NSEG);
                int oy = rr / NSEG, ox0 = (rr % NSEG) << 4;
                int iy = 2 * oy - 1 + r, ix = 2 * ox0 - 1 + s;
                if ((unsigned)iy < (unsigned)HIN && (unsigned)ix < (unsigned)WIN) {
                    GLOAD_LDS16(in + (size_t)(((n * CGI + ch) * HIN + iy) * WIN + ix) * 8, ldst);
                } else {
                    uint4 zz = {0u, 0u, 0u, 0u};
                    T[i] = zz;
                }
            }
        }
        for (int ib = 0; ib < WBu; ib += 256) {
            int i = ib + tid;
            int tap = i / COTILE, co = i % COTILE;
            GLOAD_LDS16(wcvt + (size_t)((ch * 16 + tap) * COUT + cobase + co) * 8,
                        wS + ib + (wid << 6));
        }
        __syncthreads();
        #pragma unroll
        for (int ky = 0; ky < 4; ++ky) {
            short8 Af[MBW]; short8 Bf[NWF];
            #pragma unroll
            for (int im = 0; im < MBW; ++im) {
                int mb = wm * MBW + im;
                Af[im] = *(const short8*)(T + (mb * 4 + ky) * SLOTW + 2 * lm + q);
            }
            #pragma unroll
            for (int inf = 0; inf < NWF; ++inf)
                Bf[inf] = *(const short8*)(wS + (ky * 4 + q) * COTILE + wn * NWF * 16 + inf * 16 + lm);
            #pragma unroll
            for (int im = 0; im < MBW; ++im)
                #pragma unroll
                for (int inf = 0; inf < NWF; ++inf)
                    acc[im][inf] = mfma16(Af[im], Bf[inf], acc[im][inf]);
        }
    }
    __syncthreads();
    #pragma unroll
    for (int inf = 0; inf < NWF; ++inf) {
        int col = wn * NWF * 16 + inf * 16 + lm;
        float bv = bias[cobase + col];
        #pragma unroll
        for (int im = 0; im < MBW; ++im) {
            int pixb = (wm * MBW + im) * 16 + q * 4;
            #pragma unroll
            for (int r = 0; r < 4; ++r) {
                float v = acc[im][inf][r] + bv;
                if (RELU) v = fmaxf(v, 0.f);
                E[(pixb + r) * COTILE + col] = f2bf(v);
            }
        }
    }
    __syncthreads();
    for (int i = tid; i < MB * 16 * (COTILE / 8); i += 256) {
        int pix = i / (COTILE / 8), cg = i % (COTILE / 8);
        int mb = pix >> 4, m = pix & 15;
        int mbg = mbase + mb;
        int n = mbg / (H2 * NSEG), rr = mbg % (H2 * NSEG);
        int oy = rr / NSEG, ox0 = (rr % NSEG) << 4;
        int ox = ox0 + m;
        if (ox < W2)
            *(uint4*)(outp + (size_t)(((n * CGO + cobase / 8 + cg) * H2 + oy) * W2 + ox) * 8) =
                *(uint4*)(E + pix * COTILE + cg * 8);
    }
    if (STOREZ) {
        for (int i = tid; i < MB * 16 * COTILE; i += 256) {
            int pix = i / COTILE, co = i % COTILE;
            int mb = pix >> 4, m = pix & 15;
            int mbg = mbase + mb;
            int n = mbg / (H2 * NSEG), rr = mbg % (H2 * NSEG);
            int oy = rr / NSEG, ox0 = (rr % NSEG) << 4;
            int ox = ox0 + m;
            if (ox < W2)
                z32[(size_t)((n * COUT + cobase + co) * H2 + oy) * W2 + ox] =
                    bf2f(E[pix * COTILE + co]);
        }
    }
}

// ===========================================================================
// conv1 (CIN=3): vectorized staging (float4 covers the 4 kx taps);
// scalar fallback only at image edges.
// ===========================================================================
__global__ __launch_bounds__(256) void conv1_mfma(
    const float* __restrict__ x, const u16* __restrict__ w1c,
    const float* __restrict__ bias, u16* __restrict__ outp)
{
    constexpr int MB = 16, MBW = 4, NWF = 2, COTILE = 32, W2 = 112, H2 = 112, NSEG = 7;
    constexpr int TBu = MB * 2 * 64, WBu = 256;
    __shared__ uint4 smem[TBu + WBu];
    uint4* T1 = smem; uint4* w1S = smem + TBu;
    u16* E = (u16*)smem;

    const int tid = threadIdx.x, wid = tid >> 6, lane = tid & 63;
    const int q = lane >> 4, lm = lane & 15;
    const int wm = wid;
    const int mbase = blockIdx.x * MB;

    f32x4 acc[MBW][NWF];
    #pragma unroll
    for (int a = 0; a < MBW; ++a)
        #pragma unroll
        for (int b = 0; b < NWF; ++b) {
            acc[a][b][0] = 0.f; acc[a][b][1] = 0.f;
            acc[a][b][2] = 0.f; acc[a][b][3] = 0.f;
        }

    for (int i = tid; i < TBu; i += 256) {
        int mb = i >> 7; int r = i & 127;
        int h = r >> 6; int r2 = r & 63;
        int ky = r2 >> 4; int m = r2 & 15;
        int mbg = mbase + mb;
        int n = mbg / (H2 * NSEG), rr = mbg % (H2 * NSEG);
        int oy = rr / NSEG, ox0 = (rr % NSEG) << 4;
        int iy = 2 * oy - 1 + ky;
        int ixb = 2 * (ox0 + m) - 1;
        int ci0 = 2 * h;
        uint4 vv;
        const float* rowp = x + ((size_t)(n * 3 + ci0) * 224 + iy) * 224;
        if ((unsigned)iy < 224u && ixb >= 0 && ixb <= 220) {
            float4 a = *(const float4*)(rowp + ixb);
            float4 bq;
            if (h == 0) bq = *(const float4*)(rowp + 224 * 224 + ixb);
            else { bq.x = 0.f; bq.y = 0.f; bq.z = 0.f; bq.w = 0.f; }
            vv.x = (u32)f2bf(a.x) | ((u32)f2bf(bq.x) << 16);
            vv.y = (u32)f2bf(a.y) | ((u32)f2bf(bq.y) << 16);
            vv.z = (u32)f2bf(a.z) | ((u32)f2bf(bq.z) << 16);
            vv.w = (u32)f2bf(a.w) | ((u32)f2bf(bq.w) << 16);
        } else {
            u32 u[4];
            #pragma unroll
            for (int kx = 0; kx < 4; ++kx) {
                float v0 = 0.f, v1 = 0.f;
                int ix = ixb + kx;
                if ((unsigned)iy < 224u && (unsigned)ix < 224u) {
                    v0 = rowp[ix];
                    if (ci0 + 1 < 3) v1 = rowp[224 * 224 + ix];
                }
                u[kx] = (u32)f2bf(v0) | ((u32)f2bf(v1) << 16);
            }
            vv.x = u[0]; vv.y = u[1]; vv.z = u[2]; vv.w = u[3];
        }
        T1[i] = vv;
    }
    if (tid < 256) {
        w1S[tid] = *(const uint4*)(w1c + (size_t)tid * 8);
    }
    __syncthreads();
    #pragma unroll
    for (int h = 0; h < 2; ++h) {
        short8 Af[MBW]; short8 Bf[NWF];
        #pragma unroll
        for (int im = 0; im < MBW; ++im) {
            int mb = wm * MBW + im;
            Af[im] = *(const short8*)(T1 + (mb * 2 + h) * 64 + lane);
        }
        #pragma unroll
        for (int inf = 0; inf < NWF; ++inf)
            Bf[inf] = *(const short8*)(w1S + (h * 4 + q) * 32 + inf * 16 + lm);
        #pragma unroll
        for (int im = 0; im < MBW; ++im)
            #pragma unroll
            for (int inf = 0; inf < NWF; ++inf)
                acc[im][inf] = mfma16(Af[im], Bf[inf], acc[im][inf]);
    }
    __syncthreads();
    #pragma unroll
    for (int inf = 0; inf < NWF; ++inf) {
        int col = inf * 16 + lm;
        float bv = bias[col];
        #pragma unroll
        for (int im = 0; im < MBW; ++im) {
            int pixb = (wm * MBW + im) * 16 + q * 4;
            #pragma unroll
            for (int r = 0; r < 4; ++r) {
                float v = fmaxf(acc[im][inf][r] + bv, 0.f);
                E[(pixb + r) * COTILE + col] = f2bf(v);
            }
        }
    }
    __syncthreads();
    for (int i = tid; i < MB * 16 * (COTILE / 8); i += 256) {
        int pix = i / (COTILE / 8), cg = i % (COTILE / 8);
        int mb = pix >> 4, m = pix & 15;
        int mbg = mbase + mb;
        int n = mbg / (H2 * NSEG), rr = mbg % (H2 * NSEG);
        int oy = rr / NSEG, ox0 = (rr % NSEG) << 4;
        int ox = ox0 + m;
        *(uint4*)(outp + (size_t)(((n * 4 + cg) * H2 + oy) * W2 + ox) * 8) =
            *(uint4*)(E + pix * COTILE + cg * 8);
    }
}

// ===========================================================================
// Parity-split deconv (k=4,s=2,p=1): 4 output-parity quadrants, quad = tap.
// ===========================================================================
template<int CIN, int COUT, int COPAD, int COTILE, int Hp, int Wp, int NSEG,
         int MB, int MBW, int NWF, int RELU>
__global__ __launch_bounds__(256) void deconv_mfma(
    const u16* __restrict__ in, const u16* __restrict__ dcvt,
    const float* __restrict__ bias, u16* __restrict__ outp)
{
    constexpr int CHUNKS = CIN / 8, CGI = CIN / 8, CGO = COUT / 8;
    constexpr int SLOTW = 17;
    constexpr int NF = COTILE / 16, WM = MB / MBW, WN = NF / NWF;
    static_assert(WM * WN == 4, "wave layout");
    constexpr int BPP = 64 * Hp * NSEG / MB;
    constexpr int TBu = MB * 2 * SLOTW, WBu = 4 * COTILE;
    constexpr int EBu = (MB * 16 * COTILE * 2 + 15) / 16;
    constexpr int SM = (TBu + WBu) > EBu ? (TBu + WBu) : EBu;
    __shared__ uint4 smem[SM];
    uint4* T = smem; uint4* wS = smem + TBu;
    u16* E = (u16*)smem;

    const int tid = threadIdx.x, wid = tid >> 6, lane = tid & 63;
    const int q = lane >> 4, lm = lane & 15;
    const int wm = wid / WN, wn = wid % WN;
    const int par = blockIdx.x / BPP;
    const int py = par >> 1, px = par & 1;
    const int mbase = (blockIdx.x % BPP) * MB;
    const int cobase = blockIdx.y * COTILE;

    f32x4 acc[MBW][NWF];
    #pragma unroll
    for (int a = 0; a < MBW; ++a)
        #pragma unroll
        for (int b = 0; b < NWF; ++b) {
            acc[a][b][0] = 0.f; acc[a][b][1] = 0.f;
            acc[a][b][2] = 0.f; acc[a][b][3] = 0.f;
        }

    for (int ch = 0; ch < CHUNKS; ++ch) {
        __syncthreads();
        for (int ib = 0; ib < TBu; ib += 256) {
            int i = ib + tid;
            uint4* ldst = T + ib + (wid << 6);
            if (i < TBu) {
                int mb = i / (2 * SLOTW), r2 = i % (2 * SLOTW);
                int rr_ = r2 / SLOTW, s = r2 % SLOTW;
                int mbg = mbase + mb;
                int n = mbg / (Hp * NSEG), rm = mbg % (Hp * NSEG);
                int oyp = rm / NSEG, u0 = (rm % NSEG) << 4;
                int iy = oyp + (1 - py) - 1 + rr_;
                int ix = u0 + (1 - px) - 1 + s;
                if ((unsigned)iy < (unsigned)Hp && (unsigned)ix < (unsigned)Wp) {
                    GLOAD_LDS16(in + (size_t)(((n * CGI + ch) * Hp + iy) * Wp + ix) * 8, ldst);
                } else {
                    uint4 zz = {0u, 0u, 0u, 0u};
                    T[i] = zz;
                }
            }
        }
        for (int ib = 0; ib < WBu; ib += 256) {
            int i = ib + tid;
            if (i < WBu) {
                int qq = i / COTILE, co = i % COTILE;
                GLOAD_LDS16(dcvt + (size_t)((ch * 16 + par * 4 + qq) * COPAD + cobase + co) * 8,
                            wS + ib + (wid << 6));
            }
        }
        __syncthreads();
        {
            short8 Af[MBW]; short8 Bf[NWF];
            #pragma unroll
            for (int im = 0; im < MBW; ++im) {
                int mb = wm * MBW + im;
                Af[im] = *(const short8*)(T + (mb * 2 + (1 - (q >> 1))) * SLOTW + lm + 1 - (q & 1));
            }
            #pragma unroll
            for (int inf = 0; inf < NWF; ++inf)
                Bf[inf] = *(const short8*)(wS + q * COTILE + wn * NWF * 16 + inf * 16 + lm);
            #pragma unroll
            for (int im = 0; im < MBW; ++im)
                #pragma unroll
                for (int inf = 0; inf < NWF; ++inf)
                    acc[im][inf] = mfma16(Af[im], Bf[inf], acc[im][inf]);
        }
    }
    __syncthreads();
    #pragma unroll
    for (int inf = 0; inf < NWF; ++inf) {
        int col = wn * NWF * 16 + inf * 16 + lm;
        float bv = bias[cobase + col];
        #pragma unroll
        for (int im = 0; im < MBW; ++im) {
            int pixb = (wm * MBW + im) * 16 + q * 4;
            #pragma unroll
            for (int r = 0; r < 4; ++r) {
                float v = acc[im][inf][r] + bv;
                if (RELU) v = fmaxf(v, 0.f);
                E[(pixb + r) * COTILE + col] = f2bf(v);
            }
        }
    }
    __syncthreads();
    for (int i = tid; i < MB * 16 * (COTILE / 8); i += 256) {
        int pix = i / (COTILE / 8), cg = i % (COTILE / 8);
        int mb = pix >> 4, m = pix & 15;
        int mbg = mbase + mb;
        int n = mbg / (Hp * NSEG), rm = mbg % (Hp * NSEG);
        int oyp = rm / NSEG, u0 = (rm % NSEG) << 4;
        int u = u0 + m;
        if (u < Wp) {
            int ox = 2 * u + (px ? 0 : 1);
            int oy = 2 * oyp + (py ? 0 : 1);
            *(uint4*)(outp + (size_t)(((n * CGO + cobase / 8 + cg) * (2 * Hp) + oy) * (2 * Wp) + ox) * 8) =
                *(uint4*)(E + pix * COTILE + cg * 8);
        }
    }
}

// ===========================================================================
// deconv4: all 4 parity quadrants per block; fused sigmoid + recon-loss.
// ===========================================================================
__global__ __launch_bounds__(256) void deconv4_mfma(
    const u16* __restrict__ in, const u16* __restrict__ dcvt,
    const float* __restrict__ bias, float* __restrict__ outp,
    const float* __restrict__ xref, float* __restrict__ bpart)
{
    constexpr int Hp = 112, Wp = 112, NSEG = 7, MB = 16, MBW = 4;
    constexpr int CGI = 4, CHUNKS = 4;
    constexpr int TROW = 3, TCOL = 18;
    constexpr int TBu = MB * TROW * TCOL;   // 864 uint4
    __shared__ uint4 smem[TBu + 1024];
    __shared__ float red[4];
    uint4* T = smem; uint4* wS = smem + TBu;
    float* Ef = (float*)smem;               // 3072 f32 = 12KB

    const int tid = threadIdx.x, wid = tid >> 6, lane = tid & 63;
    const int q = lane >> 4, lm = lane & 15;
    const int wm = wid;
    const int mbase = blockIdx.x * MB;

    f32x4 acc[4][MBW];
    #pragma unroll
    for (int p = 0; p < 4; ++p)
        #pragma unroll
        for (int a = 0; a < MBW; ++a) {
            acc[p][a][0] = 0.f; acc[p][a][1] = 0.f; acc[p][a][2] = 0.f; acc[p][a][3] = 0.f;
        }

    for (int ib = 0; ib < 1024; ib += 256)
        GLOAD_LDS16(dcvt + (size_t)(ib + tid) * 8, wS + ib + (wid << 6));

    for (int ch = 0; ch < CHUNKS; ++ch) {
        __syncthreads();
        for (int ib = 0; ib < TBu; ib += 256) {
            int i = ib + tid;
            uint4* ldst = T + ib + (wid << 6);
            if (i < TBu) {
                int mb = i / (TROW * TCOL), r2 = i % (TROW * TCOL);
                int r = r2 / TCOL, s = r2 % TCOL;
                int mbg = mbase + mb;
                int n = mbg / (Hp * NSEG), rm = mbg % (Hp * NSEG);
                int oyp = rm / NSEG, u0 = (rm % NSEG) << 4;
                int iy = oyp - 1 + r;
                int ix = u0 - 1 + s;
                if ((unsigned)iy < (unsigned)Hp && (unsigned)ix < (unsigned)Wp) {
                    GLOAD_LDS16(in + (size_t)(((n * CGI + ch) * Hp + iy) * Wp + ix) * 8, ldst);
                } else {
                    uint4 zz = {0u, 0u, 0u, 0u};
                    T[i] = zz;
                }
            }
        }
        __syncthreads();
        #pragma unroll
        for (int par = 0; par < 4; ++par) {
            const int py = par >> 1, px = par & 1;
            short8 Bf = *(const short8*)(wS + (ch * 16 + par * 4 + q) * 16 + lm);
            #pragma unroll
            for (int im = 0; im < MBW; ++im) {
                int mb = wm * MBW + im;
                short8 Af = *(const short8*)(T + (mb * TROW + (2 - py - (q >> 1))) * TCOL
                                             + lm + 2 - px - (q & 1));
                acc[par][im] = mfma16(Af, Bf, acc[par][im]);
            }
        }
    }

    __syncthreads();
    if (lm < 3) {
        float bv = bias[lm];
        #pragma unroll
        for (int par = 0; par < 4; ++par)
            #pragma unroll
            for (int im = 0; im < MBW; ++im)
                #pragma unroll
                for (int r = 0; r < 4; ++r)
                    Ef[(((wm * MBW + im) * 16 + q * 4 + r) * 4 + par) * 3 + lm] =
                        acc[par][im][r] + bv;
    }
    __syncthreads();
    float lsum = 0.f;
    #pragma unroll
    for (int k = 0; k < 3; ++k) {
        int i = k * 256 + tid;
        int mb = i / 48, rem = i % 48;
        int row = rem / 24, rem2 = rem % 24;
        int co = rem2 / 8, ox4 = rem2 % 8;
        int mbg = mbase + mb;
        int n = mbg / (Hp * NSEG), rm = mbg % (Hp * NSEG);
        int oyp = rm / NSEG, u0 = (rm % NSEG) << 4;
        int pA = row ? 1 : 3, pB = row ? 0 : 2;
        int uL = 2 * ox4, uH = uL + 1;
        float v0 = Ef[((mb * 16 + uL) * 4 + pA) * 3 + co];
        float v1 = Ef[((mb * 16 + uL) * 4 + pB) * 3 + co];
        float v2 = Ef[((mb * 16 + uH) * 4 + pA) * 3 + co];
        float v3 = Ef[((mb * 16 + uH) * 4 + pB) * 3 + co];
        float4 sv;
        sv.x = 1.f / (1.f + expf(-v0));
        sv.y = 1.f / (1.f + expf(-v1));
        sv.z = 1.f / (1.f + expf(-v2));
        sv.w = 1.f / (1.f + expf(-v3));
        size_t ro = ((size_t)(n * 3 + co) * 224 + 2 * oyp + row) * 224 + 2 * u0 + 4 * ox4;
        float4 x4 = *(const float4*)(xref + ro);
        *(float4*)(outp + ro) = sv;
        float d0 = sv.x - x4.x, d1 = sv.y - x4.y, d2 = sv.z - x4.z, d3 = sv.w - x4.w;
        lsum += d0 * d0 + d1 * d1 + d2 * d2 + d3 * d3;
    }
    #pragma unroll
    for (int off = 32; off > 0; off >>= 1)
        lsum += __shfl_down(lsum, off, 64);
    if (lane == 0) red[wid] = lsum;
    __syncthreads();
    if (tid == 0)
        bpart[blockIdx.x] = red[0] + red[1] + red[2] + red[3];
}

// ===========================================================================
// VQ dot GEMM: M=64, N=4000, K=12544 (14 k-splits). Coalesced cooperative
// staging with XOR-swizzled LDS layout (same involution on write and read).
// ===========================================================================
__global__ __launch_bounds__(256) void vq_gemm(
    const float* __restrict__ z32, const float* __restrict__ emb,
    float* __restrict__ P, float* __restrict__ normp)
{
    __shared__ uint4 As[8 * 64];     // 8KB
    __shared__ uint4 Bs[8 * 256];    // 32KB
    __shared__ float Ns[256 * 8];    // 8KB norm partials [row][k8]
    const int tid = threadIdx.x, wid = tid >> 6, lane = tid & 63;
    const int q = lane >> 4, lm = lane & 15;
    const int jt = blockIdx.x, ks = blockIdx.y;
    const int k8s = tid & 7;         // k8 slice staged by this thread
    const int rb2 = tid >> 3;        // 0..31 row base (B staging)

    f32x4 acc[4][4];
    #pragma unroll
    for (int a = 0; a < 4; ++a)
        #pragma unroll
        for (int b = 0; b < 4; ++b) {
            acc[a][b][0] = 0.f; acc[a][b][1] = 0.f; acc[a][b][2] = 0.f; acc[a][b][3] = 0.f;
        }
    float nsum[8];
    #pragma unroll
    for (int it = 0; it < 8; ++it) nsum[it] = 0.f;

    for (int ch = 0; ch < 14; ++ch) {
        __syncthreads();
        // A: 64 rows x 64 k; 8 lanes x 32B contiguous per row
        #pragma unroll
        for (int it = 0; it < 2; ++it) {
            int i = tid + it * 256;
            int k8 = i & 7, m = i >> 3;
            const float* ap = z32 + (size_t)m * 12544 + ks * 896 + ch * 64 + k8 * 8;
            float4 f0 = *(const float4*)(ap);
            float4 f1 = *(const float4*)(ap + 4);
            As[k8 * 64 + (m ^ k8)] = pack8(f0, f1);
        }
        // B: 256 rows x 64 k; coalesced; per-row norm partial per k8 slice
        #pragma unroll
        for (int it = 0; it < 8; ++it) {
            int r = rb2 + 32 * it;
            int jg = jt * 256 + r;
            int jc = jg < 4000 ? jg : 3999;
            const float* bp = emb + (size_t)jc * 12544 + ks * 896 + ch * 64 + k8s * 8;
            float4 fa = *(const float4*)(bp);
            float4 fb = *(const float4*)(bp + 4);
            nsum[it] += fa.x * fa.x + fa.y * fa.y + fa.z * fa.z + fa.w * fa.w
                      + fb.x * fb.x + fb.y * fb.y + fb.z * fb.z + fb.w * fb.w;
            Bs[k8s * 256 + (r ^ k8s)] = pack8(fa, fb);
        }
        __syncthreads();
        #pragma unroll
        for (int kk = 0; kk < 2; ++kk) {
            short8 Af[4]; short8 Bf[4];
            int k8x = kk * 4 + q;
            #pragma unroll
            for (int mf = 0; mf < 4; ++mf)
                Af[mf] = *(const short8*)(As + k8x * 64 + ((mf * 16 + lm) ^ k8x));
            #pragma unroll
            for (int nf = 0; nf < 4; ++nf)
                Bf[nf] = *(const short8*)(Bs + k8x * 256 + ((wid * 64 + nf * 16 + lm) ^ k8x));
            #pragma unroll
            for (int mf = 0; mf < 4; ++mf)
                #pragma unroll
                for (int nf = 0; nf < 4; ++nf)
                    acc[mf][nf] = mfma16(Af[mf], Bf[nf], acc[mf][nf]);
        }
    }
    // norm reduce: 8 partials per row
    __syncthreads();
    #pragma unroll
    for (int it = 0; it < 8; ++it)
        Ns[(rb2 + 32 * it) * 8 + k8s] = nsum[it];
    __syncthreads();
    {
        float s = 0.f;
        #pragma unroll
        for (int f = 0; f < 8; ++f) s += Ns[tid * 8 + f];
        int jg2 = jt * 256 + tid;
        if (jg2 < 4000) normp[ks * 4000 + jg2] = s;
    }
    #pragma unroll
    for (int mf = 0; mf < 4; ++mf)
        #pragma unroll
        for (int nf = 0; nf < 4; ++nf) {
            int j = jt * 256 + wid * 64 + nf * 16 + lm;
            if (j < 4000) {
                #pragma unroll
                for (int r = 0; r < 4; ++r) {
                    int b = mf * 16 + q * 4 + r;
                    P[(size_t)(ks * 64 + b) * 4000 + j] = acc[mf][nf][r];
                }
            }
        }
}

// Fused argmin + gather -> Qb + vq partial loss.
__global__ __launch_bounds__(256) void vq_argmin_gather(
    const float* __restrict__ P, const float* __restrict__ normp,
    const float* __restrict__ emb, const float* __restrict__ z32,
    u16* __restrict__ Qb, float* __restrict__ vacc)
{
    const int b = blockIdx.x;
    const int tid = threadIdx.x;
    float best = 3.4e38f;
    int bidx = 0x7fffffff;
    for (int j = tid; j < 4000; j += 256) {
        float dot = 0.f, nrm = 0.f;
        #pragma unroll
        for (int s = 0; s < 14; ++s) {
            dot += P[(size_t)(s * 64 + b) * 4000 + j];
            nrm += normp[s * 4000 + j];
        }
        float d = nrm - 2.f * dot;
        if (d < best) { best = d; bidx = j; }
    }
    __shared__ float sv[256];
    __shared__ int si[256];
    sv[tid] = best; si[tid] = bidx;
    __syncthreads();
    for (int off = 128; off > 0; off >>= 1) {
        if (tid < off) {
            float v2 = sv[tid + off]; int i2 = si[tid + off];
            if (v2 < sv[tid] || (v2 == sv[tid] && i2 < si[tid])) { sv[tid] = v2; si[tid] = i2; }
        }
        __syncthreads();
    }
    const int code = si[0];
    const float* e = emb + (size_t)code * 12544;
    const float* zb = z32 + (size_t)b * 12544;
    float ls = 0.f;
    for (int d = tid; d < 12544; d += 256) {
        float ev = e[d];
        int co = d / 196, rem = d % 196;
        int y = rem / 14, xx = rem % 14;
        Qb[((size_t)((b * 8 + (co >> 3)) * 14 + y) * 14 + xx) * 8 + (co & 7)] = f2bf(ev);
        float df = ev - zb[d];
        ls += df * df;
    }
    #pragma unroll
    for (int off = 32; off > 0; off >>= 1)
        ls += __shfl_down(ls, off, 64);
    if ((tid & 63) == 0) atomicAdd(vacc, ls);
}

__global__ __launch_bounds__(256) void reduce_final(
    const float* __restrict__ bpart, const float* __restrict__ vacc,
    float* __restrict__ tail)
{
    const int tid = threadIdx.x;
    float s = 0.f;
    for (int i = tid; i < 3136; i += 256) s += bpart[i];
    #pragma unroll
    for (int off = 32; off > 0; off >>= 1)
        s += __shfl_down(s, off, 64);
    __shared__ float red[4];
    if ((tid & 63) == 0) red[tid >> 6] = s;
    __syncthreads();
    if (tid == 0) {
        float rsum = red[0] + red[1] + red[2] + red[3];
        float recon = rsum * (1.f / 9633792.f);
        float vq = 1.25f * vacc[0] * (1.f / 802816.f);
        tail[0] = recon + vq;
        tail[1] = recon;
        tail[2] = vq;
    }
}

// ---------------------------------------------------------------------------
extern "C" void kernel_launch(void* const* d_in, const int* in_sizes, int n_in,
                              void* d_out, int out_size, void* d_ws, size_t ws_size,
                              hipStream_t stream)
{
    const float* x   = (const float*)d_in[0];
    const float* ew1 = (const float*)d_in[1];
    const float* eb1 = (const float*)d_in[2];
    const float* ew2 = (const float*)d_in[3];
    const float* eb2 = (const float*)d_in[4];
    const float* ew3 = (const float*)d_in[5];
    const float* eb3 = (const float*)d_in[6];
    const float* ew4 = (const float*)d_in[7];
    const float* eb4 = (const float*)d_in[8];
    const float* emb = (const float*)d_in[9];
    const float* dw1 = (const float*)d_in[10];
    const float* db1 = (const float*)d_in[11];
    const float* dw2 = (const float*)d_in[12];
    const float* db2 = (const float*)d_in[13];
    const float* dw3 = (const float*)d_in[14];
    const float* db3 = (const float*)d_in[15];
    const float* dw4 = (const float*)d_in[16];
    const float* db4 = (const float*)d_in[17];
    float* out = (float*)d_out;

    size_t off = 0;
    char* base = (char*)d_ws;
    auto nxt = [&](size_t bytes) -> char* {
        char* p = base + off;
        off = (off + bytes + 255) & ~(size_t)255;
        return p;
    };
    u16*   A1    = (u16*)nxt(25690112ull * 2);
    u16*   A2    = (u16*)nxt(12845056ull * 2);
    u16*   A3    = (u16*)nxt(6422528ull * 2);
    float* z32   = (float*)nxt(802816ull * 4);
    u16*   Qb    = (u16*)nxt(802816ull * 2);
    float* P     = (float*)nxt(14ull * 64 * 4000 * 4);
    float* normp = (float*)nxt(14ull * 4000 * 4);
    u16*   w1c   = (u16*)nxt(2048ull * 2);
    u16*   wc2   = (u16*)nxt(32768ull * 2);
    u16*   wc3   = (u16*)nxt(131072ull * 2);
    u16*   wc4   = (u16*)nxt(131072ull * 2);
    u16*   wd1   = (u16*)nxt(131072ull * 2);
    u16*   wd2   = (u16*)nxt(131072ull * 2);
    u16*   wd3   = (u16*)nxt(32768ull * 2);
    u16*   wd4   = (u16*)nxt(8192ull * 2);
    float* accp  = (float*)nxt(512);
    float* bpart = (float*)nxt(3136ull * 4);
    u16*   D1 = A3;
    u16*   D2 = A2;
    u16*   D3 = A1;

    hipMemsetAsync(accp, 0, 8, stream);

    prep_all<<<2344, 256, 0, stream>>>(ew1, ew2, ew3, ew4, dw1, dw2, dw3, dw4,
                                       w1c, wc2, wc3, wc4, wd1, wd2, wd3, wd4);

    // ---- encoder ----
    conv1_mfma<<<3136, 256, 0, stream>>>(x, w1c, eb1, A1);
    conv_mfma<32, 64, 64, 56, 56, 4, 16, 8, 2, 1, 0>
        <<<dim3(896, 1), 256, 0, stream>>>(A1, wc2, eb2, A2, nullptr);
    conv_mfma<64, 128, 64, 28, 28, 2, 8, 4, 2, 1, 0>
        <<<dim3(448, 2), 256, 0, stream>>>(A2, wc3, eb3, A3, nullptr);
    conv_mfma<128, 64, 64, 14, 14, 1, 8, 2, 4, 0, 1>
        <<<dim3(112, 1), 256, 0, stream>>>(A3, wc4, eb4, Qb, z32);

    // ---- VQ ----
    vq_gemm<<<dim3(16, 14), 256, 0, stream>>>(z32, emb, P, normp);
    vq_argmin_gather<<<64, 256, 0, stream>>>(P, normp, emb, z32, Qb, accp);

    // ---- decoder ----
    deconv_mfma<64, 128, 128, 64, 14, 14, 1, 8, 4, 2, 1>
        <<<dim3(448, 2), 256, 0, stream>>>(Qb, wd1, db1, D1);
    deconv_mfma<128, 64, 64, 64, 28, 28, 2, 16, 8, 2, 1>
        <<<dim3(896, 1), 256, 0, stream>>>(D1, wd2, db2, D2);
    deconv_mfma<64, 32, 32, 32, 56, 56, 4, 16, 8, 1, 1>
        <<<dim3(3584, 1), 256, 0, stream>>>(D2, wd3, db3, D3);
    deconv4_mfma<<<3136, 256, 0, stream>>>(D3, wd4, db4, out, x, bpart);

    reduce_final<<<1, 256, 0, stream>>>(bpart, accp, out + 9633792);
}

// Round 4
// 690.447 us; speedup vs baseline: 1.0824x; 1.0380x over previous
//
#include <hip/hip_runtime.h>
#include <math.h>

typedef unsigned short u16;
typedef unsigned int u32;
typedef __attribute__((ext_vector_type(8))) short short8;
typedef __attribute__((ext_vector_type(4))) float f32x4;

__device__ __forceinline__ u16 f2bf(float f) {
    u32 u = __float_as_uint(f);
    u = u + 0x7fffu + ((u >> 16) & 1u);
    return (u16)(u >> 16);
}
__device__ __forceinline__ float bf2f(u16 h) { return __uint_as_float(((u32)h) << 16); }

__device__ __forceinline__ f32x4 mfma16(short8 a, short8 b, f32x4 c) {
    return __builtin_amdgcn_mfma_f32_16x16x32_bf16(a, b, c, 0, 0, 0);
}

__device__ __forceinline__ uint4 pack8(float4 a, float4 b) {
    uint4 r;
    r.x = (u32)f2bf(a.x) | ((u32)f2bf(a.y) << 16);
    r.y = (u32)f2bf(a.z) | ((u32)f2bf(a.w) << 16);
    r.z = (u32)f2bf(b.x) | ((u32)f2bf(b.y) << 16);
    r.w = (u32)f2bf(b.z) | ((u32)f2bf(b.w) << 16);
    return r;
}

// Async global->LDS 16B: LDS dest is wave-uniform base + lane*16.
#define GLOAD_LDS16(gsrc, ldst)                                                      \
    __builtin_amdgcn_global_load_lds(                                                \
        (__attribute__((address_space(1))) u32*)(gsrc),                              \
        (__attribute__((address_space(3))) u32*)(ldst), 16, 0, 0)

// ===========================================================================
// Fused weight prep (one launch).
// ===========================================================================
__device__ __forceinline__ void prep1_item(const float* __restrict__ w,
                                           u16* __restrict__ o, int i)
{
    int j = i & 7; int kx = j >> 1, cp = j & 1;
    int r = i >> 3;
    int co = r & 31; int r2 = r >> 5;
    int ky = r2 & 3; int h = r2 >> 2;
    int ci = 2 * h + cp;
    o[i] = (ci < 3) ? f2bf(w[((co * 3 + ci) * 16) + ky * 4 + kx]) : (u16)0;
}
__device__ __forceinline__ void prepc_item(const float* __restrict__ w,
                                           u16* __restrict__ o, int CIN, int COUT, int i)
{
    int j = i & 7; int r = i >> 3;
    int co = r % COUT; int r2 = r / COUT;
    int tap = r2 & 15; int ch = r2 >> 4;
    int ci = ch * 8 + j;
    o[i] = f2bf(w[((size_t)co * CIN + ci) * 16 + tap]);
}
__device__ __forceinline__ void prepd_item(const float* __restrict__ w,
                                           u16* __restrict__ o, int CIN, int COUT,
                                           int COPAD, int i)
{
    int j = i & 7; int r = i >> 3;
    int co = r % COPAD; int r2 = r / COPAD;
    int t16 = r2 & 15; int ch = r2 >> 4;
    int py = t16 >> 3, px = (t16 >> 2) & 1, qq = t16 & 3;
    int ta = qq >> 1, tb = qq & 1;
    int ky = py + 2 * ta, kx = px + 2 * tb;
    int ci = ch * 8 + j;
    o[i] = (co < COUT) ? f2bf(w[(((size_t)ci * COUT + co) * 16) + ky * 4 + kx]) : (u16)0;
}

__global__ __launch_bounds__(256) void prep_all(
    const float* __restrict__ ew1, const float* __restrict__ ew2,
    const float* __restrict__ ew3, const float* __restrict__ ew4,
    const float* __restrict__ dw1, const float* __restrict__ dw2,
    const float* __restrict__ dw3, const float* __restrict__ dw4,
    u16* __restrict__ w1c, u16* __restrict__ wc2,
    u16* __restrict__ wc3, u16* __restrict__ wc4,
    u16* __restrict__ wd1, u16* __restrict__ wd2,
    u16* __restrict__ wd3, u16* __restrict__ wd4)
{
    int i = blockIdx.x * 256 + threadIdx.x;
    if (i < 2048) { prep1_item(ew1, w1c, i); return; }
    i -= 2048;
    if (i < 32768)  { prepc_item(ew2, wc2, 32, 64, i); return; }
    i -= 32768;
    if (i < 131072) { prepc_item(ew3, wc3, 64, 128, i); return; }
    i -= 131072;
    if (i < 131072) { prepc_item(ew4, wc4, 128, 64, i); return; }
    i -= 131072;
    if (i < 131072) { prepd_item(dw1, wd1, 64, 128, 128, i); return; }
    i -= 131072;
    if (i < 131072) { prepd_item(dw2, wd2, 128, 64, 64, i); return; }
    i -= 131072;
    if (i < 32768)  { prepd_item(dw3, wd3, 64, 32, 32, i); return; }
    i -= 32768;
    if (i < 8192)   { prepd_item(dw4, wd4, 32, 3, 16, i); return; }
}

// ===========================================================================
// Generic conv (k=4,s=2,p=1) implicit-GEMM MFMA kernel (global_load_lds).
// ===========================================================================
template<int CIN, int COUT, int COTILE, int H2, int W2, int NSEG, int MB,
         int MBW, int NWF, int RELU, int STOREZ>
__global__ __launch_bounds__(256) void conv_mfma(
    const u16* __restrict__ in, const u16* __restrict__ wcvt,
    const float* __restrict__ bias, u16* __restrict__ outp,
    float* __restrict__ z32)
{
    constexpr int CHUNKS = CIN / 8, CGI = CIN / 8, CGO = COUT / 8;
    constexpr int HIN = H2 * 2, WIN = W2 * 2, SLOTW = 35;
    constexpr int NF = COTILE / 16, WM = MB / MBW, WN = NF / NWF;
    static_assert(WM * WN == 4, "wave layout");
    constexpr int TBu = MB * 4 * SLOTW, WBu = 16 * COTILE;
    constexpr int EBu = (MB * 16 * COTILE * 2 + 15) / 16;
    constexpr int SM = (TBu + WBu) > EBu ? (TBu + WBu) : EBu;
    __shared__ uint4 smem[SM];
    uint4* T = smem; uint4* wS = smem + TBu;
    u16* E = (u16*)smem;

    const int tid = threadIdx.x, wid = tid >> 6, lane = tid & 63;
    const int q = lane >> 4, lm = lane & 15;
    const int wm = wid / WN, wn = wid % WN;
    const int cobase = blockIdx.y * COTILE;
    const int mbase = blockIdx.x * MB;

    f32x4 acc[MBW][NWF];
    #pragma unroll
    for (int a = 0; a < MBW; ++a)
        #pragma unroll
        for (int b = 0; b < NWF; ++b) {
            acc[a][b][0] = 0.f; acc[a][b][1] = 0.f;
            acc[a][b][2] = 0.f; acc[a][b][3] = 0.f;
        }

    for (int ch = 0; ch < CHUNKS; ++ch) {
        __syncthreads();
        for (int ib = 0; ib < TBu; ib += 256) {
            int i = ib + tid;
            uint4* ldst = T + ib + (wid << 6);
            if (i < TBu) {
                int mb = i / (4 * SLOTW), r2 = i % (4 * SLOTW);
                int r = r2 / SLOTW, s = r2 % SLOTW;
                int mbg = mbase + mb;
                int n = mbg / (H2 * NSEG), rr = mbg % (H2 * NSEG);
                int oy = rr / NSEG, ox0 = (rr % NSEG) << 4;
                int iy = 2 * oy - 1 + r, ix = 2 * ox0 - 1 + s;
                if ((unsigned)iy < (unsigned)HIN && (unsigned)ix < (unsigned)WIN) {
                    GLOAD_LDS16(in + (size_t)(((n * CGI + ch) * HIN + iy) * WIN + ix) * 8, ldst);
                } else {
                    uint4 zz = {0u, 0u, 0u, 0u};
                    T[i] = zz;
                }
            }
        }
        for (int ib = 0; ib < WBu; ib += 256) {
            int i = ib + tid;
            int tap = i / COTILE, co = i % COTILE;
            GLOAD_LDS16(wcvt + (size_t)((ch * 16 + tap) * COUT + cobase + co) * 8,
                        wS + ib + (wid << 6));
        }
        __syncthreads();
        #pragma unroll
        for (int ky = 0; ky < 4; ++ky) {
            short8 Af[MBW]; short8 Bf[NWF];
            #pragma unroll
            for (int im = 0; im < MBW; ++im) {
                int mb = wm * MBW + im;
                Af[im] = *(const short8*)(T + (mb * 4 + ky) * SLOTW + 2 * lm + q);
            }
            #pragma unroll
            for (int inf = 0; inf < NWF; ++inf)
                Bf[inf] = *(const short8*)(wS + (ky * 4 + q) * COTILE + wn * NWF * 16 + inf * 16 + lm);
            #pragma unroll
            for (int im = 0; im < MBW; ++im)
                #pragma unroll
                for (int inf = 0; inf < NWF; ++inf)
                    acc[im][inf] = mfma16(Af[im], Bf[inf], acc[im][inf]);
        }
    }
    __syncthreads();
    #pragma unroll
    for (int inf = 0; inf < NWF; ++inf) {
        int col = wn * NWF * 16 + inf * 16 + lm;
        float bv = bias[cobase + col];
        #pragma unroll
        for (int im = 0; im < MBW; ++im) {
            int pixb = (wm * MBW + im) * 16 + q * 4;
            #pragma unroll
            for (int r = 0; r < 4; ++r) {
                float v = acc[im][inf][r] + bv;
                if (RELU) v = fmaxf(v, 0.f);
                E[(pixb + r) * COTILE + col] = f2bf(v);
            }
        }
    }
    __syncthreads();
    for (int i = tid; i < MB * 16 * (COTILE / 8); i += 256) {
        int pix = i / (COTILE / 8), cg = i % (COTILE / 8);
        int mb = pix >> 4, m = pix & 15;
        int mbg = mbase + mb;
        int n = mbg / (H2 * NSEG), rr = mbg % (H2 * NSEG);
        int oy = rr / NSEG, ox0 = (rr % NSEG) << 4;
        int ox = ox0 + m;
        if (ox < W2)
            *(uint4*)(outp + (size_t)(((n * CGO + cobase / 8 + cg) * H2 + oy) * W2 + ox) * 8) =
                *(uint4*)(E + pix * COTILE + cg * 8);
    }
    if (STOREZ) {
        for (int i = tid; i < MB * 16 * COTILE; i += 256) {
            int pix = i / COTILE, co = i % COTILE;
            int mb = pix >> 4, m = pix & 15;
            int mbg = mbase + mb;
            int n = mbg / (H2 * NSEG), rr = mbg % (H2 * NSEG);
            int oy = rr / NSEG, ox0 = (rr % NSEG) << 4;
            int ox = ox0 + m;
            if (ox < W2)
                z32[(size_t)((n * COUT + cobase + co) * H2 + oy) * W2 + ox] =
                    bf2f(E[pix * COTILE + co]);
        }
    }
}

// ===========================================================================
// conv1 (CIN=3) special: quad = ky, j = kx*2+cp (ci=2h+cp), 2 halves h.
// (R1-verified scalar staging; float4 variant regressed — odd ixb is only
//  4B-aligned so the dwordx4 loads split.)
// ===========================================================================
__global__ __launch_bounds__(256) void conv1_mfma(
    const float* __restrict__ x, const u16* __restrict__ w1c,
    const float* __restrict__ bias, u16* __restrict__ outp)
{
    constexpr int MB = 16, MBW = 4, NWF = 2, COTILE = 32, W2 = 112, H2 = 112, NSEG = 7;
    constexpr int TBu = MB * 2 * 64, WBu = 256;
    __shared__ uint4 smem[TBu + WBu];
    uint4* T1 = smem; uint4* w1S = smem + TBu;
    u16* E = (u16*)smem;

    const int tid = threadIdx.x, wid = tid >> 6, lane = tid & 63;
    const int q = lane >> 4, lm = lane & 15;
    const int wm = wid;
    const int mbase = blockIdx.x * MB;

    f32x4 acc[MBW][NWF];
    #pragma unroll
    for (int a = 0; a < MBW; ++a)
        #pragma unroll
        for (int b = 0; b < NWF; ++b) {
            acc[a][b][0] = 0.f; acc[a][b][1] = 0.f;
            acc[a][b][2] = 0.f; acc[a][b][3] = 0.f;
        }

    for (int i = tid; i < TBu; i += 256) {
        int mb = i >> 7; int r = i & 127;
        int h = r >> 6; int r2 = r & 63;
        int ky = r2 >> 4; int m = r2 & 15;
        int mbg = mbase + mb;
        int n = mbg / (H2 * NSEG), rr = mbg % (H2 * NSEG);
        int oy = rr / NSEG, ox0 = (rr % NSEG) << 4;
        int iy = 2 * oy - 1 + ky;
        int ixb = 2 * (ox0 + m) - 1;
        u32 u[4];
        #pragma unroll
        for (int kx = 0; kx < 4; ++kx) {
            float v0 = 0.f, v1 = 0.f;
            int ix = ixb + kx;
            if ((unsigned)iy < 224u && (unsigned)ix < 224u) {
                int ci0 = 2 * h;
                v0 = x[((size_t)(n * 3 + ci0) * 224 + iy) * 224 + ix];
                if (ci0 + 1 < 3) v1 = x[((size_t)(n * 3 + ci0 + 1) * 224 + iy) * 224 + ix];
            }
            u[kx] = (u32)f2bf(v0) | ((u32)f2bf(v1) << 16);
        }
        uint4 vv; vv.x = u[0]; vv.y = u[1]; vv.z = u[2]; vv.w = u[3];
        T1[i] = vv;
    }
    if (tid < 256) {
        w1S[tid] = *(const uint4*)(w1c + (size_t)tid * 8);
    }
    __syncthreads();
    #pragma unroll
    for (int h = 0; h < 2; ++h) {
        short8 Af[MBW]; short8 Bf[NWF];
        #pragma unroll
        for (int im = 0; im < MBW; ++im) {
            int mb = wm * MBW + im;
            Af[im] = *(const short8*)(T1 + (mb * 2 + h) * 64 + lane);
        }
        #pragma unroll
        for (int inf = 0; inf < NWF; ++inf)
            Bf[inf] = *(const short8*)(w1S + (h * 4 + q) * 32 + inf * 16 + lm);
        #pragma unroll
        for (int im = 0; im < MBW; ++im)
            #pragma unroll
            for (int inf = 0; inf < NWF; ++inf)
                acc[im][inf] = mfma16(Af[im], Bf[inf], acc[im][inf]);
    }
    __syncthreads();
    #pragma unroll
    for (int inf = 0; inf < NWF; ++inf) {
        int col = inf * 16 + lm;
        float bv = bias[col];
        #pragma unroll
        for (int im = 0; im < MBW; ++im) {
            int pixb = (wm * MBW + im) * 16 + q * 4;
            #pragma unroll
            for (int r = 0; r < 4; ++r) {
                float v = fmaxf(acc[im][inf][r] + bv, 0.f);
                E[(pixb + r) * COTILE + col] = f2bf(v);
            }
        }
    }
    __syncthreads();
    for (int i = tid; i < MB * 16 * (COTILE / 8); i += 256) {
        int pix = i / (COTILE / 8), cg = i % (COTILE / 8);
        int mb = pix >> 4, m = pix & 15;
        int mbg = mbase + mb;
        int n = mbg / (H2 * NSEG), rr = mbg % (H2 * NSEG);
        int oy = rr / NSEG, ox0 = (rr % NSEG) << 4;
        int ox = ox0 + m;
        *(uint4*)(outp + (size_t)(((n * 4 + cg) * H2 + oy) * W2 + ox) * 8) =
            *(uint4*)(E + pix * COTILE + cg * 8);
    }
}

// ===========================================================================
// Parity-split deconv (k=4,s=2,p=1): 4 output-parity quadrants, quad = tap.
// ===========================================================================
template<int CIN, int COUT, int COPAD, int COTILE, int Hp, int Wp, int NSEG,
         int MB, int MBW, int NWF, int RELU>
__global__ __launch_bounds__(256) void deconv_mfma(
    const u16* __restrict__ in, const u16* __restrict__ dcvt,
    const float* __restrict__ bias, u16* __restrict__ outp)
{
    constexpr int CHUNKS = CIN / 8, CGI = CIN / 8, CGO = COUT / 8;
    constexpr int SLOTW = 17;
    constexpr int NF = COTILE / 16, WM = MB / MBW, WN = NF / NWF;
    static_assert(WM * WN == 4, "wave layout");
    constexpr int BPP = 64 * Hp * NSEG / MB;
    constexpr int TBu = MB * 2 * SLOTW, WBu = 4 * COTILE;
    constexpr int EBu = (MB * 16 * COTILE * 2 + 15) / 16;
    constexpr int SM = (TBu + WBu) > EBu ? (TBu + WBu) : EBu;
    __shared__ uint4 smem[SM];
    uint4* T = smem; uint4* wS = smem + TBu;
    u16* E = (u16*)smem;

    const int tid = threadIdx.x, wid = tid >> 6, lane = tid & 63;
    const int q = lane >> 4, lm = lane & 15;
    const int wm = wid / WN, wn = wid % WN;
    const int par = blockIdx.x / BPP;
    const int py = par >> 1, px = par & 1;
    const int mbase = (blockIdx.x % BPP) * MB;
    const int cobase = blockIdx.y * COTILE;

    f32x4 acc[MBW][NWF];
    #pragma unroll
    for (int a = 0; a < MBW; ++a)
        #pragma unroll
        for (int b = 0; b < NWF; ++b) {
            acc[a][b][0] = 0.f; acc[a][b][1] = 0.f;
            acc[a][b][2] = 0.f; acc[a][b][3] = 0.f;
        }

    for (int ch = 0; ch < CHUNKS; ++ch) {
        __syncthreads();
        for (int ib = 0; ib < TBu; ib += 256) {
            int i = ib + tid;
            uint4* ldst = T + ib + (wid << 6);
            if (i < TBu) {
                int mb = i / (2 * SLOTW), r2 = i % (2 * SLOTW);
                int rr_ = r2 / SLOTW, s = r2 % SLOTW;
                int mbg = mbase + mb;
                int n = mbg / (Hp * NSEG), rm = mbg % (Hp * NSEG);
                int oyp = rm / NSEG, u0 = (rm % NSEG) << 4;
                int iy = oyp + (1 - py) - 1 + rr_;
                int ix = u0 + (1 - px) - 1 + s;
                if ((unsigned)iy < (unsigned)Hp && (unsigned)ix < (unsigned)Wp) {
                    GLOAD_LDS16(in + (size_t)(((n * CGI + ch) * Hp + iy) * Wp + ix) * 8, ldst);
                } else {
                    uint4 zz = {0u, 0u, 0u, 0u};
                    T[i] = zz;
                }
            }
        }
        for (int ib = 0; ib < WBu; ib += 256) {
            int i = ib + tid;
            if (i < WBu) {
                int qq = i / COTILE, co = i % COTILE;
                GLOAD_LDS16(dcvt + (size_t)((ch * 16 + par * 4 + qq) * COPAD + cobase + co) * 8,
                            wS + ib + (wid << 6));
            }
        }
        __syncthreads();
        {
            short8 Af[MBW]; short8 Bf[NWF];
            #pragma unroll
            for (int im = 0; im < MBW; ++im) {
                int mb = wm * MBW + im;
                Af[im] = *(const short8*)(T + (mb * 2 + (1 - (q >> 1))) * SLOTW + lm + 1 - (q & 1));
            }
            #pragma unroll
            for (int inf = 0; inf < NWF; ++inf)
                Bf[inf] = *(const short8*)(wS + q * COTILE + wn * NWF * 16 + inf * 16 + lm);
            #pragma unroll
            for (int im = 0; im < MBW; ++im)
                #pragma unroll
                for (int inf = 0; inf < NWF; ++inf)
                    acc[im][inf] = mfma16(Af[im], Bf[inf], acc[im][inf]);
        }
    }
    __syncthreads();
    #pragma unroll
    for (int inf = 0; inf < NWF; ++inf) {
        int col = wn * NWF * 16 + inf * 16 + lm;
        float bv = bias[cobase + col];
        #pragma unroll
        for (int im = 0; im < MBW; ++im) {
            int pixb = (wm * MBW + im) * 16 + q * 4;
            #pragma unroll
            for (int r = 0; r < 4; ++r) {
                float v = acc[im][inf][r] + bv;
                if (RELU) v = fmaxf(v, 0.f);
                E[(pixb + r) * COTILE + col] = f2bf(v);
            }
        }
    }
    __syncthreads();
    for (int i = tid; i < MB * 16 * (COTILE / 8); i += 256) {
        int pix = i / (COTILE / 8), cg = i % (COTILE / 8);
        int mb = pix >> 4, m = pix & 15;
        int mbg = mbase + mb;
        int n = mbg / (Hp * NSEG), rm = mbg % (Hp * NSEG);
        int oyp = rm / NSEG, u0 = (rm % NSEG) << 4;
        int u = u0 + m;
        if (u < Wp) {
            int ox = 2 * u + (px ? 0 : 1);
            int oy = 2 * oyp + (py ? 0 : 1);
            *(uint4*)(outp + (size_t)(((n * CGO + cobase / 8 + cg) * (2 * Hp) + oy) * (2 * Wp) + ox) * 8) =
                *(uint4*)(E + pix * COTILE + cg * 8);
        }
    }
}

// ===========================================================================
// deconv4: all 4 parity quadrants per block; fused sigmoid + recon-loss.
// ===========================================================================
__global__ __launch_bounds__(256) void deconv4_mfma(
    const u16* __restrict__ in, const u16* __restrict__ dcvt,
    const float* __restrict__ bias, float* __restrict__ outp,
    const float* __restrict__ xref, float* __restrict__ bpart)
{
    constexpr int Hp = 112, Wp = 112, NSEG = 7, MB = 16, MBW = 4;
    constexpr int CGI = 4, CHUNKS = 4;
    constexpr int TROW = 3, TCOL = 18;
    constexpr int TBu = MB * TROW * TCOL;   // 864 uint4
    __shared__ uint4 smem[TBu + 1024];
    __shared__ float red[4];
    uint4* T = smem; uint4* wS = smem + TBu;
    float* Ef = (float*)smem;               // 3072 f32 = 12KB

    const int tid = threadIdx.x, wid = tid >> 6, lane = tid & 63;
    const int q = lane >> 4, lm = lane & 15;
    const int wm = wid;
    const int mbase = blockIdx.x * MB;

    f32x4 acc[4][MBW];
    #pragma unroll
    for (int p = 0; p < 4; ++p)
        #pragma unroll
        for (int a = 0; a < MBW; ++a) {
            acc[p][a][0] = 0.f; acc[p][a][1] = 0.f; acc[p][a][2] = 0.f; acc[p][a][3] = 0.f;
        }

    for (int ib = 0; ib < 1024; ib += 256)
        GLOAD_LDS16(dcvt + (size_t)(ib + tid) * 8, wS + ib + (wid << 6));

    for (int ch = 0; ch < CHUNKS; ++ch) {
        __syncthreads();
        for (int ib = 0; ib < TBu; ib += 256) {
            int i = ib + tid;
            uint4* ldst = T + ib + (wid << 6);
            if (i < TBu) {
                int mb = i / (TROW * TCOL), r2 = i % (TROW * TCOL);
                int r = r2 / TCOL, s = r2 % TCOL;
                int mbg = mbase + mb;
                int n = mbg / (Hp * NSEG), rm = mbg % (Hp * NSEG);
                int oyp = rm / NSEG, u0 = (rm % NSEG) << 4;
                int iy = oyp - 1 + r;
                int ix = u0 - 1 + s;
                if ((unsigned)iy < (unsigned)Hp && (unsigned)ix < (unsigned)Wp) {
                    GLOAD_LDS16(in + (size_t)(((n * CGI + ch) * Hp + iy) * Wp + ix) * 8, ldst);
                } else {
                    uint4 zz = {0u, 0u, 0u, 0u};
                    T[i] = zz;
                }
            }
        }
        __syncthreads();
        #pragma unroll
        for (int par = 0; par < 4; ++par) {
            const int py = par >> 1, px = par & 1;
            short8 Bf = *(const short8*)(wS + (ch * 16 + par * 4 + q) * 16 + lm);
            #pragma unroll
            for (int im = 0; im < MBW; ++im) {
                int mb = wm * MBW + im;
                short8 Af = *(const short8*)(T + (mb * TROW + (2 - py - (q >> 1))) * TCOL
                                             + lm + 2 - px - (q & 1));
                acc[par][im] = mfma16(Af, Bf, acc[par][im]);
            }
        }
    }

    __syncthreads();
    if (lm < 3) {
        float bv = bias[lm];
        #pragma unroll
        for (int par = 0; par < 4; ++par)
            #pragma unroll
            for (int im = 0; im < MBW; ++im)
                #pragma unroll
                for (int r = 0; r < 4; ++r)
                    Ef[(((wm * MBW + im) * 16 + q * 4 + r) * 4 + par) * 3 + lm] =
                        acc[par][im][r] + bv;
    }
    __syncthreads();
    float lsum = 0.f;
    #pragma unroll
    for (int k = 0; k < 3; ++k) {
        int i = k * 256 + tid;
        int mb = i / 48, rem = i % 48;
        int row = rem / 24, rem2 = rem % 24;
        int co = rem2 / 8, ox4 = rem2 % 8;
        int mbg = mbase + mb;
        int n = mbg / (Hp * NSEG), rm = mbg % (Hp * NSEG);
        int oyp = rm / NSEG, u0 = (rm % NSEG) << 4;
        int pA = row ? 1 : 3, pB = row ? 0 : 2;
        int uL = 2 * ox4, uH = uL + 1;
        float v0 = Ef[((mb * 16 + uL) * 4 + pA) * 3 + co];
        float v1 = Ef[((mb * 16 + uL) * 4 + pB) * 3 + co];
        float v2 = Ef[((mb * 16 + uH) * 4 + pA) * 3 + co];
        float v3 = Ef[((mb * 16 + uH) * 4 + pB) * 3 + co];
        float4 sv;
        sv.x = 1.f / (1.f + expf(-v0));
        sv.y = 1.f / (1.f + expf(-v1));
        sv.z = 1.f / (1.f + expf(-v2));
        sv.w = 1.f / (1.f + expf(-v3));
        size_t ro = ((size_t)(n * 3 + co) * 224 + 2 * oyp + row) * 224 + 2 * u0 + 4 * ox4;
        float4 x4 = *(const float4*)(xref + ro);
        *(float4*)(outp + ro) = sv;
        float d0 = sv.x - x4.x, d1 = sv.y - x4.y, d2 = sv.z - x4.z, d3 = sv.w - x4.w;
        lsum += d0 * d0 + d1 * d1 + d2 * d2 + d3 * d3;
    }
    #pragma unroll
    for (int off = 32; off > 0; off >>= 1)
        lsum += __shfl_down(lsum, off, 64);
    if (lane == 0) red[wid] = lsum;
    __syncthreads();
    if (tid == 0)
        bpart[blockIdx.x] = red[0] + red[1] + red[2] + red[3];
}

// ===========================================================================
// VQ dot GEMM (bf16 MFMA): M=64, N=4000, K=12544, K split 28x (448 each).
// R1-verified per-thread-row staging; split raised 14->28 for occupancy
// (224 -> 448 blocks on 256 CUs).
// ===========================================================================
__global__ __launch_bounds__(256) void vq_gemm(
    const float* __restrict__ z32, const float* __restrict__ emb,
    float* __restrict__ P, float* __restrict__ normp)
{
    __shared__ uint4 As[8 * 64];
    __shared__ uint4 Bs[8 * 256];
    const int tid = threadIdx.x, wid = tid >> 6, lane = tid & 63;
    const int q = lane >> 4, lm = lane & 15;
    const int jt = blockIdx.x, ks = blockIdx.y;
    const int jg = jt * 256 + tid;
    const int jc = jg < 4000 ? jg : 3999;
    const float* brow = emb + (size_t)jc * 12544 + ks * 448;
    const int m = tid & 63, ksub = tid >> 6;
    const float* arow = z32 + (size_t)m * 12544 + ks * 448 + ksub * 16;

    f32x4 acc[4][4];
    #pragma unroll
    for (int a = 0; a < 4; ++a)
        #pragma unroll
        for (int b = 0; b < 4; ++b) {
            acc[a][b][0] = 0.f; acc[a][b][1] = 0.f; acc[a][b][2] = 0.f; acc[a][b][3] = 0.f;
        }
    float nsq = 0.f;

    for (int ch = 0; ch < 7; ++ch) {
        __syncthreads();
        {
            float4 f0 = *(const float4*)(arow + ch * 64);
            float4 f1 = *(const float4*)(arow + ch * 64 + 4);
            float4 f2 = *(const float4*)(arow + ch * 64 + 8);
            float4 f3 = *(const float4*)(arow + ch * 64 + 12);
            As[(ksub * 2 + 0) * 64 + m] = pack8(f0, f1);
            As[(ksub * 2 + 1) * 64 + m] = pack8(f2, f3);
        }
        {
            const float* bp = brow + ch * 64;
            #pragma unroll
            for (int ko = 0; ko < 8; ++ko) {
                float4 fa = *(const float4*)(bp + ko * 8);
                float4 fb = *(const float4*)(bp + ko * 8 + 4);
                nsq += fa.x * fa.x + fa.y * fa.y + fa.z * fa.z + fa.w * fa.w
                     + fb.x * fb.x + fb.y * fb.y + fb.z * fb.z + fb.w * fb.w;
                Bs[ko * 256 + tid] = pack8(fa, fb);
            }
        }
        __syncthreads();
        #pragma unroll
        for (int kk = 0; kk < 2; ++kk) {
            short8 Af[4]; short8 Bf[4];
            #pragma unroll
            for (int mf = 0; mf < 4; ++mf)
                Af[mf] = *(const short8*)(As + (kk * 4 + q) * 64 + mf * 16 + lm);
            #pragma unroll
            for (int nf = 0; nf < 4; ++nf)
                Bf[nf] = *(const short8*)(Bs + (kk * 4 + q) * 256 + wid * 64 + nf * 16 + lm);
            #pragma unroll
            for (int mf = 0; mf < 4; ++mf)
                #pragma unroll
                for (int nf = 0; nf < 4; ++nf)
                    acc[mf][nf] = mfma16(Af[mf], Bf[nf], acc[mf][nf]);
        }
    }
    #pragma unroll
    for (int mf = 0; mf < 4; ++mf)
        #pragma unroll
        for (int nf = 0; nf < 4; ++nf) {
            int j = jt * 256 + wid * 64 + nf * 16 + lm;
            if (j < 4000) {
                #pragma unroll
                for (int r = 0; r < 4; ++r) {
                    int b = mf * 16 + q * 4 + r;
                    P[(size_t)(ks * 64 + b) * 4000 + j] = acc[mf][nf][r];
                }
            }
        }
    if (jg < 4000) normp[ks * 4000 + jg] = nsq;
}

// Fused argmin + gather -> Qb + vq partial loss (28 K-splits).
__global__ __launch_bounds__(256) void vq_argmin_gather(
    const float* __restrict__ P, const float* __restrict__ normp,
    const float* __restrict__ emb, const float* __restrict__ z32,
    u16* __restrict__ Qb, float* __restrict__ vacc)
{
    const int b = blockIdx.x;
    const int tid = threadIdx.x;
    float best = 3.4e38f;
    int bidx = 0x7fffffff;
    for (int j = tid; j < 4000; j += 256) {
        float dot = 0.f, nrm = 0.f;
        #pragma unroll
        for (int s = 0; s < 28; ++s) {
            dot += P[(size_t)(s * 64 + b) * 4000 + j];
            nrm += normp[s * 4000 + j];
        }
        float d = nrm - 2.f * dot;
        if (d < best) { best = d; bidx = j; }
    }
    __shared__ float sv[256];
    __shared__ int si[256];
    sv[tid] = best; si[tid] = bidx;
    __syncthreads();
    for (int off = 128; off > 0; off >>= 1) {
        if (tid < off) {
            float v2 = sv[tid + off]; int i2 = si[tid + off];
            if (v2 < sv[tid] || (v2 == sv[tid] && i2 < si[tid])) { sv[tid] = v2; si[tid] = i2; }
        }
        __syncthreads();
    }
    const int code = si[0];
    const float* e = emb + (size_t)code * 12544;
    const float* zb = z32 + (size_t)b * 12544;
    float ls = 0.f;
    for (int d = tid; d < 12544; d += 256) {
        float ev = e[d];
        int co = d / 196, rem = d % 196;
        int y = rem / 14, xx = rem % 14;
        Qb[((size_t)((b * 8 + (co >> 3)) * 14 + y) * 14 + xx) * 8 + (co & 7)] = f2bf(ev);
        float df = ev - zb[d];
        ls += df * df;
    }
    #pragma unroll
    for (int off = 32; off > 0; off >>= 1)
        ls += __shfl_down(ls, off, 64);
    if ((tid & 63) == 0) atomicAdd(vacc, ls);
}

__global__ __launch_bounds__(256) void reduce_final(
    const float* __restrict__ bpart, const float* __restrict__ vacc,
    float* __restrict__ tail)
{
    const int tid = threadIdx.x;
    float s = 0.f;
    for (int i = tid; i < 3136; i += 256) s += bpart[i];
    #pragma unroll
    for (int off = 32; off > 0; off >>= 1)
        s += __shfl_down(s, off, 64);
    __shared__ float red[4];
    if ((tid & 63) == 0) red[tid >> 6] = s;
    __syncthreads();
    if (tid == 0) {
        float rsum = red[0] + red[1] + red[2] + red[3];
        float recon = rsum * (1.f / 9633792.f);
        float vq = 1.25f * vacc[0] * (1.f / 802816.f);
        tail[0] = recon + vq;
        tail[1] = recon;
        tail[2] = vq;
    }
}

// ---------------------------------------------------------------------------
extern "C" void kernel_launch(void* const* d_in, const int* in_sizes, int n_in,
                              void* d_out, int out_size, void* d_ws, size_t ws_size,
                              hipStream_t stream)
{
    const float* x   = (const float*)d_in[0];
    const float* ew1 = (const float*)d_in[1];
    const float* eb1 = (const float*)d_in[2];
    const float* ew2 = (const float*)d_in[3];
    const float* eb2 = (const float*)d_in[4];
    const float* ew3 = (const float*)d_in[5];
    const float* eb3 = (const float*)d_in[6];
    const float* ew4 = (const float*)d_in[7];
    const float* eb4 = (const float*)d_in[8];
    const float* emb = (const float*)d_in[9];
    const float* dw1 = (const float*)d_in[10];
    const float* db1 = (const float*)d_in[11];
    const float* dw2 = (const float*)d_in[12];
    const float* db2 = (const float*)d_in[13];
    const float* dw3 = (const float*)d_in[14];
    const float* db3 = (const float*)d_in[15];
    const float* dw4 = (const float*)d_in[16];
    const float* db4 = (const float*)d_in[17];
    float* out = (float*)d_out;

    size_t off = 0;
    char* base = (char*)d_ws;
    auto nxt = [&](size_t bytes) -> char* {
        char* p = base + off;
        off = (off + bytes + 255) & ~(size_t)255;
        return p;
    };
    u16*   A1    = (u16*)nxt(25690112ull * 2);
    u16*   A2    = (u16*)nxt(12845056ull * 2);
    u16*   A3    = (u16*)nxt(6422528ull * 2);
    float* z32   = (float*)nxt(802816ull * 4);
    u16*   Qb    = (u16*)nxt(802816ull * 2);
    float* P     = (float*)nxt(28ull * 64 * 4000 * 4);
    float* normp = (float*)nxt(28ull * 4000 * 4);
    u16*   w1c   = (u16*)nxt(2048ull * 2);
    u16*   wc2   = (u16*)nxt(32768ull * 2);
    u16*   wc3   = (u16*)nxt(131072ull * 2);
    u16*   wc4   = (u16*)nxt(131072ull * 2);
    u16*   wd1   = (u16*)nxt(131072ull * 2);
    u16*   wd2   = (u16*)nxt(131072ull * 2);
    u16*   wd3   = (u16*)nxt(32768ull * 2);
    u16*   wd4   = (u16*)nxt(8192ull * 2);
    float* accp  = (float*)nxt(512);
    float* bpart = (float*)nxt(3136ull * 4);
    u16*   D1 = A3;
    u16*   D2 = A2;
    u16*   D3 = A1;

    hipMemsetAsync(accp, 0, 8, stream);

    prep_all<<<2344, 256, 0, stream>>>(ew1, ew2, ew3, ew4, dw1, dw2, dw3, dw4,
                                       w1c, wc2, wc3, wc4, wd1, wd2, wd3, wd4);

    // ---- encoder ----
    conv1_mfma<<<3136, 256, 0, stream>>>(x, w1c, eb1, A1);
    conv_mfma<32, 64, 64, 56, 56, 4, 16, 8, 2, 1, 0>
        <<<dim3(896, 1), 256, 0, stream>>>(A1, wc2, eb2, A2, nullptr);
    conv_mfma<64, 128, 64, 28, 28, 2, 8, 4, 2, 1, 0>
        <<<dim3(448, 2), 256, 0, stream>>>(A2, wc3, eb3, A3, nullptr);
    conv_mfma<128, 64, 64, 14, 14, 1, 4, 2, 2, 0, 1>
        <<<dim3(224, 1), 256, 0, stream>>>(A3, wc4, eb4, Qb, z32);

    // ---- VQ ----
    vq_gemm<<<dim3(16, 28), 256, 0, stream>>>(z32, emb, P, normp);
    vq_argmin_gather<<<64, 256, 0, stream>>>(P, normp, emb, z32, Qb, accp);

    // ---- decoder ----
    deconv_mfma<64, 128, 128, 64, 14, 14, 1, 8, 4, 2, 1>
        <<<dim3(448, 2), 256, 0, stream>>>(Qb, wd1, db1, D1);
    deconv_mfma<128, 64, 64, 64, 28, 28, 2, 16, 8, 2, 1>
        <<<dim3(896, 1), 256, 0, stream>>>(D1, wd2, db2, D2);
    deconv_mfma<64, 32, 32, 32, 56, 56, 4, 16, 8, 1, 1>
        <<<dim3(3584, 1), 256, 0, stream>>>(D2, wd3, db3, D3);
    deconv4_mfma<<<3136, 256, 0, stream>>>(D3, wd4, db4, out, x, bpart);

    reduce_final<<<1, 256, 0, stream>>>(bpart, accp, out + 9633792);
}

// Round 5
// 671.479 us; speedup vs baseline: 1.1130x; 1.0282x over previous
//
#include <hip/hip_runtime.h>
#include <math.h>

typedef unsigned short u16;
typedef unsigned int u32;
typedef __attribute__((ext_vector_type(8))) short short8;
typedef __attribute__((ext_vector_type(4))) float f32x4;

__device__ __forceinline__ u16 f2bf(float f) {
    u32 u = __float_as_uint(f);
    u = u + 0x7fffu + ((u >> 16) & 1u);
    return (u16)(u >> 16);
}
__device__ __forceinline__ float bf2f(u16 h) { return __uint_as_float(((u32)h) << 16); }

__device__ __forceinline__ f32x4 mfma16(short8 a, short8 b, f32x4 c) {
    return __builtin_amdgcn_mfma_f32_16x16x32_bf16(a, b, c, 0, 0, 0);
}

__device__ __forceinline__ uint4 pack8(float4 a, float4 b) {
    uint4 r;
    r.x = (u32)f2bf(a.x) | ((u32)f2bf(a.y) << 16);
    r.y = (u32)f2bf(a.z) | ((u32)f2bf(a.w) << 16);
    r.z = (u32)f2bf(b.x) | ((u32)f2bf(b.y) << 16);
    r.w = (u32)f2bf(b.z) | ((u32)f2bf(b.w) << 16);
    return r;
}

// Async global->LDS 16B: LDS dest is wave-uniform base + lane*16.
#define GLOAD_LDS16(gsrc, ldst)                                                      \
    __builtin_amdgcn_global_load_lds(                                                \
        (__attribute__((address_space(1))) u32*)(gsrc),                              \
        (__attribute__((address_space(3))) u32*)(ldst), 16, 0, 0)

// ===========================================================================
// Fused weight prep (one launch).
// ===========================================================================
__device__ __forceinline__ void prep1_item(const float* __restrict__ w,
                                           u16* __restrict__ o, int i)
{
    int j = i & 7; int kx = j >> 1, cp = j & 1;
    int r = i >> 3;
    int co = r & 31; int r2 = r >> 5;
    int ky = r2 & 3; int h = r2 >> 2;
    int ci = 2 * h + cp;
    o[i] = (ci < 3) ? f2bf(w[((co * 3 + ci) * 16) + ky * 4 + kx]) : (u16)0;
}
__device__ __forceinline__ void prepc_item(const float* __restrict__ w,
                                           u16* __restrict__ o, int CIN, int COUT, int i)
{
    int j = i & 7; int r = i >> 3;
    int co = r % COUT; int r2 = r / COUT;
    int tap = r2 & 15; int ch = r2 >> 4;
    int ci = ch * 8 + j;
    o[i] = f2bf(w[((size_t)co * CIN + ci) * 16 + tap]);
}
__device__ __forceinline__ void prepd_item(const float* __restrict__ w,
                                           u16* __restrict__ o, int CIN, int COUT,
                                           int COPAD, int i)
{
    int j = i & 7; int r = i >> 3;
    int co = r % COPAD; int r2 = r / COPAD;
    int t16 = r2 & 15; int ch = r2 >> 4;
    int py = t16 >> 3, px = (t16 >> 2) & 1, qq = t16 & 3;
    int ta = qq >> 1, tb = qq & 1;
    int ky = py + 2 * ta, kx = px + 2 * tb;
    int ci = ch * 8 + j;
    o[i] = (co < COUT) ? f2bf(w[(((size_t)ci * COUT + co) * 16) + ky * 4 + kx]) : (u16)0;
}

__global__ __launch_bounds__(256) void prep_all(
    const float* __restrict__ ew1, const float* __restrict__ ew2,
    const float* __restrict__ ew3, const float* __restrict__ ew4,
    const float* __restrict__ dw1, const float* __restrict__ dw2,
    const float* __restrict__ dw3, const float* __restrict__ dw4,
    u16* __restrict__ w1c, u16* __restrict__ wc2,
    u16* __restrict__ wc3, u16* __restrict__ wc4,
    u16* __restrict__ wd1, u16* __restrict__ wd2,
    u16* __restrict__ wd3, u16* __restrict__ wd4)
{
    int i = blockIdx.x * 256 + threadIdx.x;
    if (i < 2048) { prep1_item(ew1, w1c, i); return; }
    i -= 2048;
    if (i < 32768)  { prepc_item(ew2, wc2, 32, 64, i); return; }
    i -= 32768;
    if (i < 131072) { prepc_item(ew3, wc3, 64, 128, i); return; }
    i -= 131072;
    if (i < 131072) { prepc_item(ew4, wc4, 128, 64, i); return; }
    i -= 131072;
    if (i < 131072) { prepd_item(dw1, wd1, 64, 128, 128, i); return; }
    i -= 131072;
    if (i < 131072) { prepd_item(dw2, wd2, 128, 64, 64, i); return; }
    i -= 131072;
    if (i < 32768)  { prepd_item(dw3, wd3, 64, 32, 32, i); return; }
    i -= 32768;
    if (i < 8192)   { prepd_item(dw4, wd4, 32, 3, 16, i); return; }
}

// ===========================================================================
// x -> packed bf16 pairs: xb[n][h][iy][ix] = {ci=2h lo, ci=2h+1 hi} (h=1 hi=0).
// Coalesced pre-pass so conv1 staging is 4 plain u32 loads per entry.
// ===========================================================================
__global__ __launch_bounds__(256) void x2bf(
    const float* __restrict__ x, u32* __restrict__ xb)
{
    const size_t PL = 224 * 224;
    const size_t TOT = 64 * PL;
    size_t stride = (size_t)gridDim.x * 256;
    for (size_t i = (size_t)blockIdx.x * 256 + threadIdx.x; i < TOT; i += stride) {
        size_t n = i / PL, p = i % PL;
        const float* xp = x + n * 3 * PL + p;
        float c0 = xp[0], c1 = xp[PL], c2 = xp[2 * PL];
        xb[(n * 2 + 0) * PL + p] = (u32)f2bf(c0) | ((u32)f2bf(c1) << 16);
        xb[(n * 2 + 1) * PL + p] = (u32)f2bf(c2);
    }
}

// ===========================================================================
// Generic conv (k=4,s=2,p=1) implicit-GEMM MFMA kernel (global_load_lds).
// Used for conv2/conv3 (single-buffered: doubling LDS would cut occupancy).
// ===========================================================================
template<int CIN, int COUT, int COTILE, int H2, int W2, int NSEG, int MB,
         int MBW, int NWF, int RELU, int STOREZ>
__global__ __launch_bounds__(256) void conv_mfma(
    const u16* __restrict__ in, const u16* __restrict__ wcvt,
    const float* __restrict__ bias, u16* __restrict__ outp,
    float* __restrict__ z32)
{
    constexpr int CHUNKS = CIN / 8, CGI = CIN / 8, CGO = COUT / 8;
    constexpr int HIN = H2 * 2, WIN = W2 * 2, SLOTW = 35;
    constexpr int NF = COTILE / 16, WM = MB / MBW, WN = NF / NWF;
    static_assert(WM * WN == 4, "wave layout");
    constexpr int TBu = MB * 4 * SLOTW, WBu = 16 * COTILE;
    constexpr int EBu = (MB * 16 * COTILE * 2 + 15) / 16;
    constexpr int SM = (TBu + WBu) > EBu ? (TBu + WBu) : EBu;
    __shared__ uint4 smem[SM];
    uint4* T = smem; uint4* wS = smem + TBu;
    u16* E = (u16*)smem;

    const int tid = threadIdx.x, wid = tid >> 6, lane = tid & 63;
    const int q = lane >> 4, lm = lane & 15;
    const int wm = wid / WN, wn = wid % WN;
    const int cobase = blockIdx.y * COTILE;
    const int mbase = blockIdx.x * MB;

    f32x4 acc[MBW][NWF];
    #pragma unroll
    for (int a = 0; a < MBW; ++a)
        #pragma unroll
        for (int b = 0; b < NWF; ++b) {
            acc[a][b][0] = 0.f; acc[a][b][1] = 0.f;
            acc[a][b][2] = 0.f; acc[a][b][3] = 0.f;
        }

    for (int ch = 0; ch < CHUNKS; ++ch) {
        __syncthreads();
        for (int ib = 0; ib < TBu; ib += 256) {
            int i = ib + tid;
            uint4* ldst = T + ib + (wid << 6);
            if (i < TBu) {
                int mb = i / (4 * SLOTW), r2 = i % (4 * SLOTW);
                int r = r2 / SLOTW, s = r2 % SLOTW;
                int mbg = mbase + mb;
                int n = mbg / (H2 * NSEG), rr = mbg % (H2 * NSEG);
                int oy = rr / NSEG, ox0 = (rr % NSEG) << 4;
                int iy = 2 * oy - 1 + r, ix = 2 * ox0 - 1 + s;
                if ((unsigned)iy < (unsigned)HIN && (unsigned)ix < (unsigned)WIN) {
                    GLOAD_LDS16(in + (size_t)(((n * CGI + ch) * HIN + iy) * WIN + ix) * 8, ldst);
                } else {
                    uint4 zz = {0u, 0u, 0u, 0u};
                    T[i] = zz;
                }
            }
        }
        for (int ib = 0; ib < WBu; ib += 256) {
            int i = ib + tid;
            int tap = i / COTILE, co = i % COTILE;
            GLOAD_LDS16(wcvt + (size_t)((ch * 16 + tap) * COUT + cobase + co) * 8,
                        wS + ib + (wid << 6));
        }
        __syncthreads();
        #pragma unroll
        for (int ky = 0; ky < 4; ++ky) {
            short8 Af[MBW]; short8 Bf[NWF];
            #pragma unroll
            for (int im = 0; im < MBW; ++im) {
                int mb = wm * MBW + im;
                Af[im] = *(const short8*)(T + (mb * 4 + ky) * SLOTW + 2 * lm + q);
            }
            #pragma unroll
            for (int inf = 0; inf < NWF; ++inf)
                Bf[inf] = *(const short8*)(wS + (ky * 4 + q) * COTILE + wn * NWF * 16 + inf * 16 + lm);
            #pragma unroll
            for (int im = 0; im < MBW; ++im)
                #pragma unroll
                for (int inf = 0; inf < NWF; ++inf)
                    acc[im][inf] = mfma16(Af[im], Bf[inf], acc[im][inf]);
        }
    }
    __syncthreads();
    #pragma unroll
    for (int inf = 0; inf < NWF; ++inf) {
        int col = wn * NWF * 16 + inf * 16 + lm;
        float bv = bias[cobase + col];
        #pragma unroll
        for (int im = 0; im < MBW; ++im) {
            int pixb = (wm * MBW + im) * 16 + q * 4;
            #pragma unroll
            for (int r = 0; r < 4; ++r) {
                float v = acc[im][inf][r] + bv;
                if (RELU) v = fmaxf(v, 0.f);
                E[(pixb + r) * COTILE + col] = f2bf(v);
            }
        }
    }
    __syncthreads();
    for (int i = tid; i < MB * 16 * (COTILE / 8); i += 256) {
        int pix = i / (COTILE / 8), cg = i % (COTILE / 8);
        int mb = pix >> 4, m = pix & 15;
        int mbg = mbase + mb;
        int n = mbg / (H2 * NSEG), rr = mbg % (H2 * NSEG);
        int oy = rr / NSEG, ox0 = (rr % NSEG) << 4;
        int ox = ox0 + m;
        if (ox < W2)
            *(uint4*)(outp + (size_t)(((n * CGO + cobase / 8 + cg) * H2 + oy) * W2 + ox) * 8) =
                *(uint4*)(E + pix * COTILE + cg * 8);
    }
    if (STOREZ) {
        for (int i = tid; i < MB * 16 * COTILE; i += 256) {
            int pix = i / COTILE, co = i % COTILE;
            int mb = pix >> 4, m = pix & 15;
            int mbg = mbase + mb;
            int n = mbg / (H2 * NSEG), rr = mbg % (H2 * NSEG);
            int oy = rr / NSEG, ox0 = (rr % NSEG) << 4;
            int ox = ox0 + m;
            if (ox < W2)
                z32[(size_t)((n * COUT + cobase + co) * H2 + oy) * W2 + ox] =
                    bf2f(E[pix * COTILE + co]);
        }
    }
}

// ===========================================================================
// Prefetch (2-phase) conv variant: issue next chunk's global_load_lds before
// computing current chunk; one barrier per chunk. Used for conv4 (grid <1
// block/CU -> no inter-block latency hiding; LDS doubling harmless there).
// ===========================================================================
template<int CIN, int COUT, int COTILE, int H2, int W2, int NSEG, int MB,
         int MBW, int NWF, int RELU, int STOREZ>
__global__ __launch_bounds__(256) void conv_mfma_pf(
    const u16* __restrict__ in, const u16* __restrict__ wcvt,
    const float* __restrict__ bias, u16* __restrict__ outp,
    float* __restrict__ z32)
{
    constexpr int CHUNKS = CIN / 8, CGI = CIN / 8, CGO = COUT / 8;
    constexpr int HIN = H2 * 2, WIN = W2 * 2, SLOTW = 35;
    constexpr int NF = COTILE / 16, WM = MB / MBW, WN = NF / NWF;
    static_assert(WM * WN == 4, "wave layout");
    constexpr int TBu = MB * 4 * SLOTW, WBu = 16 * COTILE;
    constexpr int BUF = TBu + WBu;
    constexpr int EBu = (MB * 16 * COTILE * 2 + 15) / 16;
    constexpr int SM = (2 * BUF) > EBu ? (2 * BUF) : EBu;
    __shared__ uint4 smem[SM];
    u16* E = (u16*)smem;

    const int tid = threadIdx.x, wid = tid >> 6, lane = tid & 63;
    const int q = lane >> 4, lm = lane & 15;
    const int wm = wid / WN, wn = wid % WN;
    const int cobase = blockIdx.y * COTILE;
    const int mbase = blockIdx.x * MB;

    f32x4 acc[MBW][NWF];
    #pragma unroll
    for (int a = 0; a < MBW; ++a)
        #pragma unroll
        for (int b = 0; b < NWF; ++b) {
            acc[a][b][0] = 0.f; acc[a][b][1] = 0.f;
            acc[a][b][2] = 0.f; acc[a][b][3] = 0.f;
        }

    auto stage = [&](int ch, uint4* buf) {
        uint4* T = buf; uint4* wS = buf + TBu;
        for (int ib = 0; ib < TBu; ib += 256) {
            int i = ib + tid;
            uint4* ldst = T + ib + (wid << 6);
            if (i < TBu) {
                int mb = i / (4 * SLOTW), r2 = i % (4 * SLOTW);
                int r = r2 / SLOTW, s = r2 % SLOTW;
                int mbg = mbase + mb;
                int n = mbg / (H2 * NSEG), rr = mbg % (H2 * NSEG);
                int oy = rr / NSEG, ox0 = (rr % NSEG) << 4;
                int iy = 2 * oy - 1 + r, ix = 2 * ox0 - 1 + s;
                if ((unsigned)iy < (unsigned)HIN && (unsigned)ix < (unsigned)WIN) {
                    GLOAD_LDS16(in + (size_t)(((n * CGI + ch) * HIN + iy) * WIN + ix) * 8, ldst);
                } else {
                    uint4 zz = {0u, 0u, 0u, 0u};
                    T[i] = zz;
                }
            }
        }
        for (int ib = 0; ib < WBu; ib += 256) {
            int i = ib + tid;
            int tap = i / COTILE, co = i % COTILE;
            GLOAD_LDS16(wcvt + (size_t)((ch * 16 + tap) * COUT + cobase + co) * 8,
                        wS + ib + (wid << 6));
        }
    };

    uint4* cur = smem;
    uint4* nxt = smem + BUF;
    stage(0, cur);
    __syncthreads();
    for (int ch = 0; ch < CHUNKS; ++ch) {
        if (ch + 1 < CHUNKS) stage(ch + 1, nxt);
        uint4* T = cur; uint4* wS = cur + TBu;
        #pragma unroll
        for (int ky = 0; ky < 4; ++ky) {
            short8 Af[MBW]; short8 Bf[NWF];
            #pragma unroll
            for (int im = 0; im < MBW; ++im) {
                int mb = wm * MBW + im;
                Af[im] = *(const short8*)(T + (mb * 4 + ky) * SLOTW + 2 * lm + q);
            }
            #pragma unroll
            for (int inf = 0; inf < NWF; ++inf)
                Bf[inf] = *(const short8*)(wS + (ky * 4 + q) * COTILE + wn * NWF * 16 + inf * 16 + lm);
            #pragma unroll
            for (int im = 0; im < MBW; ++im)
                #pragma unroll
                for (int inf = 0; inf < NWF; ++inf)
                    acc[im][inf] = mfma16(Af[im], Bf[inf], acc[im][inf]);
        }
        __syncthreads();
        uint4* t = cur; cur = nxt; nxt = t;
    }
    #pragma unroll
    for (int inf = 0; inf < NWF; ++inf) {
        int col = wn * NWF * 16 + inf * 16 + lm;
        float bv = bias[cobase + col];
        #pragma unroll
        for (int im = 0; im < MBW; ++im) {
            int pixb = (wm * MBW + im) * 16 + q * 4;
            #pragma unroll
            for (int r = 0; r < 4; ++r) {
                float v = acc[im][inf][r] + bv;
                if (RELU) v = fmaxf(v, 0.f);
                E[(pixb + r) * COTILE + col] = f2bf(v);
            }
        }
    }
    __syncthreads();
    for (int i = tid; i < MB * 16 * (COTILE / 8); i += 256) {
        int pix = i / (COTILE / 8), cg = i % (COTILE / 8);
        int mb = pix >> 4, m = pix & 15;
        int mbg = mbase + mb;
        int n = mbg / (H2 * NSEG), rr = mbg % (H2 * NSEG);
        int oy = rr / NSEG, ox0 = (rr % NSEG) << 4;
        int ox = ox0 + m;
        if (ox < W2)
            *(uint4*)(outp + (size_t)(((n * CGO + cobase / 8 + cg) * H2 + oy) * W2 + ox) * 8) =
                *(uint4*)(E + pix * COTILE + cg * 8);
    }
    if (STOREZ) {
        for (int i = tid; i < MB * 16 * COTILE; i += 256) {
            int pix = i / COTILE, co = i % COTILE;
            int mb = pix >> 4, m = pix & 15;
            int mbg = mbase + mb;
            int n = mbg / (H2 * NSEG), rr = mbg % (H2 * NSEG);
            int oy = rr / NSEG, ox0 = (rr % NSEG) << 4;
            int ox = ox0 + m;
            if (ox < W2)
                z32[(size_t)((n * COUT + cobase + co) * H2 + oy) * W2 + ox] =
                    bf2f(E[pix * COTILE + co]);
        }
    }
}

// ===========================================================================
// conv1 (CIN=3): staging from pre-packed xb (4 plain u32 loads per entry,
// zero conversions in the hot loop).
// ===========================================================================
__global__ __launch_bounds__(256) void conv1_mfma(
    const u32* __restrict__ xb, const u16* __restrict__ w1c,
    const float* __restrict__ bias, u16* __restrict__ outp)
{
    constexpr int MB = 16, MBW = 4, NWF = 2, COTILE = 32, W2 = 112, H2 = 112, NSEG = 7;
    constexpr int TBu = MB * 2 * 64, WBu = 256;
    __shared__ uint4 smem[TBu + WBu];
    uint4* T1 = smem; uint4* w1S = smem + TBu;
    u16* E = (u16*)smem;

    const int tid = threadIdx.x, wid = tid >> 6, lane = tid & 63;
    const int q = lane >> 4, lm = lane & 15;
    const int wm = wid;
    const int mbase = blockIdx.x * MB;

    f32x4 acc[MBW][NWF];
    #pragma unroll
    for (int a = 0; a < MBW; ++a)
        #pragma unroll
        for (int b = 0; b < NWF; ++b) {
            acc[a][b][0] = 0.f; acc[a][b][1] = 0.f;
            acc[a][b][2] = 0.f; acc[a][b][3] = 0.f;
        }

    for (int i = tid; i < TBu; i += 256) {
        int mb = i >> 7; int r = i & 127;
        int h = r >> 6; int r2 = r & 63;
        int ky = r2 >> 4; int m = r2 & 15;
        int mbg = mbase + mb;
        int n = mbg / (H2 * NSEG), rr = mbg % (H2 * NSEG);
        int oy = rr / NSEG, ox0 = (rr % NSEG) << 4;
        int iy = 2 * oy - 1 + ky;
        int ixb = 2 * (ox0 + m) - 1;
        const u32* rowp = xb + ((size_t)(n * 2 + h) * 224 + iy) * 224;
        bool rok = (unsigned)iy < 224u;
        uint4 vv;
        vv.x = (rok && (unsigned)(ixb + 0) < 224u) ? rowp[ixb + 0] : 0u;
        vv.y = (rok && (unsigned)(ixb + 1) < 224u) ? rowp[ixb + 1] : 0u;
        vv.z = (rok && (unsigned)(ixb + 2) < 224u) ? rowp[ixb + 2] : 0u;
        vv.w = (rok && (unsigned)(ixb + 3) < 224u) ? rowp[ixb + 3] : 0u;
        T1[i] = vv;
    }
    if (tid < 256) {
        w1S[tid] = *(const uint4*)(w1c + (size_t)tid * 8);
    }
    __syncthreads();
    #pragma unroll
    for (int h = 0; h < 2; ++h) {
        short8 Af[MBW]; short8 Bf[NWF];
        #pragma unroll
        for (int im = 0; im < MBW; ++im) {
            int mb = wm * MBW + im;
            Af[im] = *(const short8*)(T1 + (mb * 2 + h) * 64 + lane);
        }
        #pragma unroll
        for (int inf = 0; inf < NWF; ++inf)
            Bf[inf] = *(const short8*)(w1S + (h * 4 + q) * 32 + inf * 16 + lm);
        #pragma unroll
        for (int im = 0; im < MBW; ++im)
            #pragma unroll
            for (int inf = 0; inf < NWF; ++inf)
                acc[im][inf] = mfma16(Af[im], Bf[inf], acc[im][inf]);
    }
    __syncthreads();
    #pragma unroll
    for (int inf = 0; inf < NWF; ++inf) {
        int col = inf * 16 + lm;
        float bv = bias[col];
        #pragma unroll
        for (int im = 0; im < MBW; ++im) {
            int pixb = (wm * MBW + im) * 16 + q * 4;
            #pragma unroll
            for (int r = 0; r < 4; ++r) {
                float v = fmaxf(acc[im][inf][r] + bv, 0.f);
                E[(pixb + r) * COTILE + col] = f2bf(v);
            }
        }
    }
    __syncthreads();
    for (int i = tid; i < MB * 16 * (COTILE / 8); i += 256) {
        int pix = i / (COTILE / 8), cg = i % (COTILE / 8);
        int mb = pix >> 4, m = pix & 15;
        int mbg = mbase + mb;
        int n = mbg / (H2 * NSEG), rr = mbg % (H2 * NSEG);
        int oy = rr / NSEG, ox0 = (rr % NSEG) << 4;
        int ox = ox0 + m;
        *(uint4*)(outp + (size_t)(((n * 4 + cg) * H2 + oy) * W2 + ox) * 8) =
            *(uint4*)(E + pix * COTILE + cg * 8);
    }
}

// ===========================================================================
// Parity-split deconv with 2-phase prefetch (deconv1/2/3). LDS: staging
// double-buffer stays below/at the E-buffer footprint -> occupancy unchanged.
// ===========================================================================
template<int CIN, int COUT, int COPAD, int COTILE, int Hp, int Wp, int NSEG,
         int MB, int MBW, int NWF, int RELU>
__global__ __launch_bounds__(256) void deconv_mfma_pf(
    const u16* __restrict__ in, const u16* __restrict__ dcvt,
    const float* __restrict__ bias, u16* __restrict__ outp)
{
    constexpr int CHUNKS = CIN / 8, CGI = CIN / 8, CGO = COUT / 8;
    constexpr int SLOTW = 17;
    constexpr int NF = COTILE / 16, WM = MB / MBW, WN = NF / NWF;
    static_assert(WM * WN == 4, "wave layout");
    constexpr int BPP = 64 * Hp * NSEG / MB;
    constexpr int TBu = MB * 2 * SLOTW, WBu = 4 * COTILE;
    constexpr int BUF = TBu + WBu;
    constexpr int EBu = (MB * 16 * COTILE * 2 + 15) / 16;
    constexpr int SM = (2 * BUF) > EBu ? (2 * BUF) : EBu;
    __shared__ uint4 smem[SM];
    u16* E = (u16*)smem;

    const int tid = threadIdx.x, wid = tid >> 6, lane = tid & 63;
    const int q = lane >> 4, lm = lane & 15;
    const int wm = wid / WN, wn = wid % WN;
    const int par = blockIdx.x / BPP;
    const int py = par >> 1, px = par & 1;
    const int mbase = (blockIdx.x % BPP) * MB;
    const int cobase = blockIdx.y * COTILE;

    f32x4 acc[MBW][NWF];
    #pragma unroll
    for (int a = 0; a < MBW; ++a)
        #pragma unroll
        for (int b = 0; b < NWF; ++b) {
            acc[a][b][0] = 0.f; acc[a][b][1] = 0.f;
            acc[a][b][2] = 0.f; acc[a][b][3] = 0.f;
        }

    auto stage = [&](int ch, uint4* buf) {
        uint4* T = buf; uint4* wS = buf + TBu;
        for (int ib = 0; ib < TBu; ib += 256) {
            int i = ib + tid;
            uint4* ldst = T + ib + (wid << 6);
            if (i < TBu) {
                int mb = i / (2 * SLOTW), r2 = i % (2 * SLOTW);
                int rr_ = r2 / SLOTW, s = r2 % SLOTW;
                int mbg = mbase + mb;
                int n = mbg / (Hp * NSEG), rm = mbg % (Hp * NSEG);
                int oyp = rm / NSEG, u0 = (rm % NSEG) << 4;
                int iy = oyp + (1 - py) - 1 + rr_;
                int ix = u0 + (1 - px) - 1 + s;
                if ((unsigned)iy < (unsigned)Hp && (unsigned)ix < (unsigned)Wp) {
                    GLOAD_LDS16(in + (size_t)(((n * CGI + ch) * Hp + iy) * Wp + ix) * 8, ldst);
                } else {
                    uint4 zz = {0u, 0u, 0u, 0u};
                    T[i] = zz;
                }
            }
        }
        for (int ib = 0; ib < WBu; ib += 256) {
            int i = ib + tid;
            if (i < WBu) {
                int qq = i / COTILE, co = i % COTILE;
                GLOAD_LDS16(dcvt + (size_t)((ch * 16 + par * 4 + qq) * COPAD + cobase + co) * 8,
                            wS + ib + (wid << 6));
            }
        }
    };

    uint4* cur = smem;
    uint4* nxt = smem + BUF;
    stage(0, cur);
    __syncthreads();
    for (int ch = 0; ch < CHUNKS; ++ch) {
        if (ch + 1 < CHUNKS) stage(ch + 1, nxt);
        uint4* T = cur; uint4* wS = cur + TBu;
        {
            short8 Af[MBW]; short8 Bf[NWF];
            #pragma unroll
            for (int im = 0; im < MBW; ++im) {
                int mb = wm * MBW + im;
                Af[im] = *(const short8*)(T + (mb * 2 + (1 - (q >> 1))) * SLOTW + lm + 1 - (q & 1));
            }
            #pragma unroll
            for (int inf = 0; inf < NWF; ++inf)
                Bf[inf] = *(const short8*)(wS + q * COTILE + wn * NWF * 16 + inf * 16 + lm);
            #pragma unroll
            for (int im = 0; im < MBW; ++im)
                #pragma unroll
                for (int inf = 0; inf < NWF; ++inf)
                    acc[im][inf] = mfma16(Af[im], Bf[inf], acc[im][inf]);
        }
        __syncthreads();
        uint4* t = cur; cur = nxt; nxt = t;
    }
    #pragma unroll
    for (int inf = 0; inf < NWF; ++inf) {
        int col = wn * NWF * 16 + inf * 16 + lm;
        float bv = bias[cobase + col];
        #pragma unroll
        for (int im = 0; im < MBW; ++im) {
            int pixb = (wm * MBW + im) * 16 + q * 4;
            #pragma unroll
            for (int r = 0; r < 4; ++r) {
                float v = acc[im][inf][r] + bv;
                if (RELU) v = fmaxf(v, 0.f);
                E[(pixb + r) * COTILE + col] = f2bf(v);
            }
        }
    }
    __syncthreads();
    for (int i = tid; i < MB * 16 * (COTILE / 8); i += 256) {
        int pix = i / (COTILE / 8), cg = i % (COTILE / 8);
        int mb = pix >> 4, m = pix & 15;
        int mbg = mbase + mb;
        int n = mbg / (Hp * NSEG), rm = mbg % (Hp * NSEG);
        int oyp = rm / NSEG, u0 = (rm % NSEG) << 4;
        int u = u0 + m;
        if (u < Wp) {
            int ox = 2 * u + (px ? 0 : 1);
            int oy = 2 * oyp + (py ? 0 : 1);
            *(uint4*)(outp + (size_t)(((n * CGO + cobase / 8 + cg) * (2 * Hp) + oy) * (2 * Wp) + ox) * 8) =
                *(uint4*)(E + pix * COTILE + cg * 8);
        }
    }
}

// ===========================================================================
// deconv4: all 4 parity quadrants per block; fused sigmoid + recon-loss.
// ===========================================================================
__global__ __launch_bounds__(256) void deconv4_mfma(
    const u16* __restrict__ in, const u16* __restrict__ dcvt,
    const float* __restrict__ bias, float* __restrict__ outp,
    const float* __restrict__ xref, float* __restrict__ bpart)
{
    constexpr int Hp = 112, Wp = 112, NSEG = 7, MB = 16, MBW = 4;
    constexpr int CGI = 4, CHUNKS = 4;
    constexpr int TROW = 3, TCOL = 18;
    constexpr int TBu = MB * TROW * TCOL;   // 864 uint4
    __shared__ uint4 smem[TBu + 1024];
    __shared__ float red[4];
    uint4* T = smem; uint4* wS = smem + TBu;
    float* Ef = (float*)smem;               // 3072 f32 = 12KB

    const int tid = threadIdx.x, wid = tid >> 6, lane = tid & 63;
    const int q = lane >> 4, lm = lane & 15;
    const int wm = wid;
    const int mbase = blockIdx.x * MB;

    f32x4 acc[4][MBW];
    #pragma unroll
    for (int p = 0; p < 4; ++p)
        #pragma unroll
        for (int a = 0; a < MBW; ++a) {
            acc[p][a][0] = 0.f; acc[p][a][1] = 0.f; acc[p][a][2] = 0.f; acc[p][a][3] = 0.f;
        }

    for (int ib = 0; ib < 1024; ib += 256)
        GLOAD_LDS16(dcvt + (size_t)(ib + tid) * 8, wS + ib + (wid << 6));

    for (int ch = 0; ch < CHUNKS; ++ch) {
        __syncthreads();
        for (int ib = 0; ib < TBu; ib += 256) {
            int i = ib + tid;
            uint4* ldst = T + ib + (wid << 6);
            if (i < TBu) {
                int mb = i / (TROW * TCOL), r2 = i % (TROW * TCOL);
                int r = r2 / TCOL, s = r2 % TCOL;
                int mbg = mbase + mb;
                int n = mbg / (Hp * NSEG), rm = mbg % (Hp * NSEG);
                int oyp = rm / NSEG, u0 = (rm % NSEG) << 4;
                int iy = oyp - 1 + r;
                int ix = u0 - 1 + s;
                if ((unsigned)iy < (unsigned)Hp && (unsigned)ix < (unsigned)Wp) {
                    GLOAD_LDS16(in + (size_t)(((n * CGI + ch) * Hp + iy) * Wp + ix) * 8, ldst);
                } else {
                    uint4 zz = {0u, 0u, 0u, 0u};
                    T[i] = zz;
                }
            }
        }
        __syncthreads();
        #pragma unroll
        for (int par = 0; par < 4; ++par) {
            const int py = par >> 1, px = par & 1;
            short8 Bf = *(const short8*)(wS + (ch * 16 + par * 4 + q) * 16 + lm);
            #pragma unroll
            for (int im = 0; im < MBW; ++im) {
                int mb = wm * MBW + im;
                short8 Af = *(const short8*)(T + (mb * TROW + (2 - py - (q >> 1))) * TCOL
                                             + lm + 2 - px - (q & 1));
                acc[par][im] = mfma16(Af, Bf, acc[par][im]);
            }
        }
    }

    __syncthreads();
    if (lm < 3) {
        float bv = bias[lm];
        #pragma unroll
        for (int par = 0; par < 4; ++par)
            #pragma unroll
            for (int im = 0; im < MBW; ++im)
                #pragma unroll
                for (int r = 0; r < 4; ++r)
                    Ef[(((wm * MBW + im) * 16 + q * 4 + r) * 4 + par) * 3 + lm] =
                        acc[par][im][r] + bv;
    }
    __syncthreads();
    float lsum = 0.f;
    #pragma unroll
    for (int k = 0; k < 3; ++k) {
        int i = k * 256 + tid;
        int mb = i / 48, rem = i % 48;
        int row = rem / 24, rem2 = rem % 24;
        int co = rem2 / 8, ox4 = rem2 % 8;
        int mbg = mbase + mb;
        int n = mbg / (Hp * NSEG), rm = mbg % (Hp * NSEG);
        int oyp = rm / NSEG, u0 = (rm % NSEG) << 4;
        int pA = row ? 1 : 3, pB = row ? 0 : 2;
        int uL = 2 * ox4, uH = uL + 1;
        float v0 = Ef[((mb * 16 + uL) * 4 + pA) * 3 + co];
        float v1 = Ef[((mb * 16 + uL) * 4 + pB) * 3 + co];
        float v2 = Ef[((mb * 16 + uH) * 4 + pA) * 3 + co];
        float v3 = Ef[((mb * 16 + uH) * 4 + pB) * 3 + co];
        float4 sv;
        sv.x = 1.f / (1.f + expf(-v0));
        sv.y = 1.f / (1.f + expf(-v1));
        sv.z = 1.f / (1.f + expf(-v2));
        sv.w = 1.f / (1.f + expf(-v3));
        size_t ro = ((size_t)(n * 3 + co) * 224 + 2 * oyp + row) * 224 + 2 * u0 + 4 * ox4;
        float4 x4 = *(const float4*)(xref + ro);
        *(float4*)(outp + ro) = sv;
        float d0 = sv.x - x4.x, d1 = sv.y - x4.y, d2 = sv.z - x4.z, d3 = sv.w - x4.w;
        lsum += d0 * d0 + d1 * d1 + d2 * d2 + d3 * d3;
    }
    #pragma unroll
    for (int off = 32; off > 0; off >>= 1)
        lsum += __shfl_down(lsum, off, 64);
    if (lane == 0) red[wid] = lsum;
    __syncthreads();
    if (tid == 0)
        bpart[blockIdx.x] = red[0] + red[1] + red[2] + red[3];
}

// ===========================================================================
// VQ dot GEMM (bf16 MFMA): M=64, N=4000, K=12544, K split 28x (448 each).
// ===========================================================================
__global__ __launch_bounds__(256) void vq_gemm(
    const float* __restrict__ z32, const float* __restrict__ emb,
    float* __restrict__ P, float* __restrict__ normp)
{
    __shared__ uint4 As[8 * 64];
    __shared__ uint4 Bs[8 * 256];
    const int tid = threadIdx.x, wid = tid >> 6, lane = tid & 63;
    const int q = lane >> 4, lm = lane & 15;
    const int jt = blockIdx.x, ks = blockIdx.y;
    const int jg = jt * 256 + tid;
    const int jc = jg < 4000 ? jg : 3999;
    const float* brow = emb + (size_t)jc * 12544 + ks * 448;
    const int m = tid & 63, ksub = tid >> 6;
    const float* arow = z32 + (size_t)m * 12544 + ks * 448 + ksub * 16;

    f32x4 acc[4][4];
    #pragma unroll
    for (int a = 0; a < 4; ++a)
        #pragma unroll
        for (int b = 0; b < 4; ++b) {
            acc[a][b][0] = 0.f; acc[a][b][1] = 0.f; acc[a][b][2] = 0.f; acc[a][b][3] = 0.f;
        }
    float nsq = 0.f;

    for (int ch = 0; ch < 7; ++ch) {
        __syncthreads();
        {
            float4 f0 = *(const float4*)(arow + ch * 64);
            float4 f1 = *(const float4*)(arow + ch * 64 + 4);
            float4 f2 = *(const float4*)(arow + ch * 64 + 8);
            float4 f3 = *(const float4*)(arow + ch * 64 + 12);
            As[(ksub * 2 + 0) * 64 + m] = pack8(f0, f1);
            As[(ksub * 2 + 1) * 64 + m] = pack8(f2, f3);
        }
        {
            const float* bp = brow + ch * 64;
            #pragma unroll
            for (int ko = 0; ko < 8; ++ko) {
                float4 fa = *(const float4*)(bp + ko * 8);
                float4 fb = *(const float4*)(bp + ko * 8 + 4);
                nsq += fa.x * fa.x + fa.y * fa.y + fa.z * fa.z + fa.w * fa.w
                     + fb.x * fb.x + fb.y * fb.y + fb.z * fb.z + fb.w * fb.w;
                Bs[ko * 256 + tid] = pack8(fa, fb);
            }
        }
        __syncthreads();
        #pragma unroll
        for (int kk = 0; kk < 2; ++kk) {
            short8 Af[4]; short8 Bf[4];
            #pragma unroll
            for (int mf = 0; mf < 4; ++mf)
                Af[mf] = *(const short8*)(As + (kk * 4 + q) * 64 + mf * 16 + lm);
            #pragma unroll
            for (int nf = 0; nf < 4; ++nf)
                Bf[nf] = *(const short8*)(Bs + (kk * 4 + q) * 256 + wid * 64 + nf * 16 + lm);
            #pragma unroll
            for (int mf = 0; mf < 4; ++mf)
                #pragma unroll
                for (int nf = 0; nf < 4; ++nf)
                    acc[mf][nf] = mfma16(Af[mf], Bf[nf], acc[mf][nf]);
        }
    }
    #pragma unroll
    for (int mf = 0; mf < 4; ++mf)
        #pragma unroll
        for (int nf = 0; nf < 4; ++nf) {
            int j = jt * 256 + wid * 64 + nf * 16 + lm;
            if (j < 4000) {
                #pragma unroll
                for (int r = 0; r < 4; ++r) {
                    int b = mf * 16 + q * 4 + r;
                    P[(size_t)(ks * 64 + b) * 4000 + j] = acc[mf][nf][r];
                }
            }
        }
    if (jg < 4000) normp[ks * 4000 + jg] = nsq;
}

// Fused argmin + gather -> Qb + vq partial loss (28 K-splits).
__global__ __launch_bounds__(256) void vq_argmin_gather(
    const float* __restrict__ P, const float* __restrict__ normp,
    const float* __restrict__ emb, const float* __restrict__ z32,
    u16* __restrict__ Qb, float* __restrict__ vacc)
{
    const int b = blockIdx.x;
    const int tid = threadIdx.x;
    float best = 3.4e38f;
    int bidx = 0x7fffffff;
    for (int j = tid; j < 4000; j += 256) {
        float dot = 0.f, nrm = 0.f;
        #pragma unroll
        for (int s = 0; s < 28; ++s) {
            dot += P[(size_t)(s * 64 + b) * 4000 + j];
            nrm += normp[s * 4000 + j];
        }
        float d = nrm - 2.f * dot;
        if (d < best) { best = d; bidx = j; }
    }
    __shared__ float sv[256];
    __shared__ int si[256];
    sv[tid] = best; si[tid] = bidx;
    __syncthreads();
    for (int off = 128; off > 0; off >>= 1) {
        if (tid < off) {
            float v2 = sv[tid + off]; int i2 = si[tid + off];
            if (v2 < sv[tid] || (v2 == sv[tid] && i2 < si[tid])) { sv[tid] = v2; si[tid] = i2; }
        }
        __syncthreads();
    }
    const int code = si[0];
    const float* e = emb + (size_t)code * 12544;
    const float* zb = z32 + (size_t)b * 12544;
    float ls = 0.f;
    for (int d = tid; d < 12544; d += 256) {
        float ev = e[d];
        int co = d / 196, rem = d % 196;
        int y = rem / 14, xx = rem % 14;
        Qb[((size_t)((b * 8 + (co >> 3)) * 14 + y) * 14 + xx) * 8 + (co & 7)] = f2bf(ev);
        float df = ev - zb[d];
        ls += df * df;
    }
    #pragma unroll
    for (int off = 32; off > 0; off >>= 1)
        ls += __shfl_down(ls, off, 64);
    if ((tid & 63) == 0) atomicAdd(vacc, ls);
}

__global__ __launch_bounds__(256) void reduce_final(
    const float* __restrict__ bpart, const float* __restrict__ vacc,
    float* __restrict__ tail)
{
    const int tid = threadIdx.x;
    float s = 0.f;
    for (int i = tid; i < 3136; i += 256) s += bpart[i];
    #pragma unroll
    for (int off = 32; off > 0; off >>= 1)
        s += __shfl_down(s, off, 64);
    __shared__ float red[4];
    if ((tid & 63) == 0) red[tid >> 6] = s;
    __syncthreads();
    if (tid == 0) {
        float rsum = red[0] + red[1] + red[2] + red[3];
        float recon = rsum * (1.f / 9633792.f);
        float vq = 1.25f * vacc[0] * (1.f / 802816.f);
        tail[0] = recon + vq;
        tail[1] = recon;
        tail[2] = vq;
    }
}

// ---------------------------------------------------------------------------
extern "C" void kernel_launch(void* const* d_in, const int* in_sizes, int n_in,
                              void* d_out, int out_size, void* d_ws, size_t ws_size,
                              hipStream_t stream)
{
    const float* x   = (const float*)d_in[0];
    const float* ew1 = (const float*)d_in[1];
    const float* eb1 = (const float*)d_in[2];
    const float* ew2 = (const float*)d_in[3];
    const float* eb2 = (const float*)d_in[4];
    const float* ew3 = (const float*)d_in[5];
    const float* eb3 = (const float*)d_in[6];
    const float* ew4 = (const float*)d_in[7];
    const float* eb4 = (const float*)d_in[8];
    const float* emb = (const float*)d_in[9];
    const float* dw1 = (const float*)d_in[10];
    const float* db1 = (const float*)d_in[11];
    const float* dw2 = (const float*)d_in[12];
    const float* db2 = (const float*)d_in[13];
    const float* dw3 = (const float*)d_in[14];
    const float* db3 = (const float*)d_in[15];
    const float* dw4 = (const float*)d_in[16];
    const float* db4 = (const float*)d_in[17];
    float* out = (float*)d_out;

    size_t off = 0;
    char* base = (char*)d_ws;
    auto nxt = [&](size_t bytes) -> char* {
        char* p = base + off;
        off = (off + bytes + 255) & ~(size_t)255;
        return p;
    };
    u16*   A1    = (u16*)nxt(25690112ull * 2);
    u16*   A2    = (u16*)nxt(12845056ull * 2);
    u16*   A3    = (u16*)nxt(6422528ull * 2);
    float* z32   = (float*)nxt(802816ull * 4);
    u16*   Qb    = (u16*)nxt(802816ull * 2);
    float* P     = (float*)nxt(28ull * 64 * 4000 * 4);
    float* normp = (float*)nxt(28ull * 4000 * 4);
    u32*   xb    = (u32*)nxt(64ull * 2 * 224 * 224 * 4);
    u16*   w1c   = (u16*)nxt(2048ull * 2);
    u16*   wc2   = (u16*)nxt(32768ull * 2);
    u16*   wc3   = (u16*)nxt(131072ull * 2);
    u16*   wc4   = (u16*)nxt(131072ull * 2);
    u16*   wd1   = (u16*)nxt(131072ull * 2);
    u16*   wd2   = (u16*)nxt(131072ull * 2);
    u16*   wd3   = (u16*)nxt(32768ull * 2);
    u16*   wd4   = (u16*)nxt(8192ull * 2);
    float* accp  = (float*)nxt(512);
    float* bpart = (float*)nxt(3136ull * 4);
    u16*   D1 = A3;
    u16*   D2 = A2;
    u16*   D3 = A1;

    hipMemsetAsync(accp, 0, 8, stream);

    prep_all<<<2344, 256, 0, stream>>>(ew1, ew2, ew3, ew4, dw1, dw2, dw3, dw4,
                                       w1c, wc2, wc3, wc4, wd1, wd2, wd3, wd4);
    x2bf<<<2048, 256, 0, stream>>>(x, xb);

    // ---- encoder ----
    conv1_mfma<<<3136, 256, 0, stream>>>(xb, w1c, eb1, A1);
    conv_mfma<32, 64, 64, 56, 56, 4, 16, 8, 2, 1, 0>
        <<<dim3(896, 1), 256, 0, stream>>>(A1, wc2, eb2, A2, nullptr);
    conv_mfma<64, 128, 64, 28, 28, 2, 8, 4, 2, 1, 0>
        <<<dim3(448, 2), 256, 0, stream>>>(A2, wc3, eb3, A3, nullptr);
    conv_mfma_pf<128, 64, 64, 14, 14, 1, 4, 2, 2, 0, 1>
        <<<dim3(224, 1), 256, 0, stream>>>(A3, wc4, eb4, Qb, z32);

    // ---- VQ ----
    vq_gemm<<<dim3(16, 28), 256, 0, stream>>>(z32, emb, P, normp);
    vq_argmin_gather<<<64, 256, 0, stream>>>(P, normp, emb, z32, Qb, accp);

    // ---- decoder ----
    deconv_mfma_pf<64, 128, 128, 64, 14, 14, 1, 8, 4, 2, 1>
        <<<dim3(448, 2), 256, 0, stream>>>(Qb, wd1, db1, D1);
    deconv_mfma_pf<128, 64, 64, 64, 28, 28, 2, 16, 8, 2, 1>
        <<<dim3(896, 1), 256, 0, stream>>>(D1, wd2, db2, D2);
    deconv_mfma_pf<64, 32, 32, 32, 56, 56, 4, 16, 8, 1, 1>
        <<<dim3(3584, 1), 256, 0, stream>>>(D2, wd3, db3, D3);
    deconv4_mfma<<<3136, 256, 0, stream>>>(D3, wd4, db4, out, x, bpart);

    reduce_final<<<1, 256, 0, stream>>>(bpart, accp, out + 9633792);
}